// Round 9
// baseline (1841.376 us; speedup 1.0000x reference)
//
#include <hip/hip_runtime.h>
#include <math.h>

// ============================ MFMA types/helpers ============================
typedef short bf16x8 __attribute__((ext_vector_type(8)));   // 8 bf16 (4 VGPRs)
typedef float f32x4 __attribute__((ext_vector_type(4)));

#define MFMA16(a, b, c) __builtin_amdgcn_mfma_f32_16x16x32_bf16((a), (b), (c), 0, 0, 0)

__device__ inline unsigned short bf16_rn(float x) {
    unsigned u = __float_as_uint(x);
    unsigned r = u + 0x7FFFu + ((u >> 16) & 1u);
    return (unsigned short)(r >> 16);
}
__device__ inline float bf16_to_f(unsigned short h) {
    return __uint_as_float(((unsigned)h) << 16);
}
__device__ inline void split2(float x, unsigned short* hp, unsigned short* lp) {
    unsigned short h = bf16_rn(x);
    *hp = h;
    *lp = bf16_rn(x - bf16_to_f(h));
}

// ============================ workspace layout (bytes) ============================
static constexpr size_t OFF_W1SH  = 0;           // [64co][32k] shorts  (k 27..31 zero)
static constexpr size_t OFF_W1SL  = 4096;
static constexpr size_t OFF_W2SH  = 8192;        // [128co][576k] shorts, k = khw*64+ci
static constexpr size_t OFF_W2SL  = 155648;
static constexpr size_t OFF_W3SH  = 303104;      // [256co][1152k] shorts, k = khw*128+ci
static constexpr size_t OFF_W3SL  = 892928;
static constexpr size_t OFF_CODH  = 1482752;     // [1024][256] shorts (rows>=Kc zero)
static constexpr size_t OFF_CODL  = 2007040;
static constexpr size_t OFF_CNORM = 2531328;     // [1024] f32 (3e38 for >=Kc)
static constexpr size_t OFF_COUNTS= 2535424;     // [1024] int
static constexpr size_t OFF_LOSS  = 2539520;     // f32
static constexpr size_t OFF_ENC   = 2539776;     // [65536] int
static constexpr size_t OFF_BIG   = 2801920;     // y2h(67108864)+y2l(67108864)
                                                 // post-conv3 reuse: LUT f32 (33554432) + h f32 (8388608)
static constexpr size_t OFF_FLATS = 137019648;   // fh(33554432)+fl(33554432)
                                                 // post-vq reuse: fc1wsh(4194304)+fc1wsl(4194304)

// ============================ prep1: weight/code splits ============================
__global__ __launch_bounds__(256) void prep1_kernel(
    const float* __restrict__ w1, const float* __restrict__ w2,
    const float* __restrict__ w3, const float* __restrict__ code0,
    const float* __restrict__ code1, const int* __restrict__ idxp,
    unsigned short* __restrict__ w1sh, unsigned short* __restrict__ w1sl,
    unsigned short* __restrict__ w2sh, unsigned short* __restrict__ w2sl,
    unsigned short* __restrict__ w3sh, unsigned short* __restrict__ w3sl,
    unsigned short* __restrict__ codh, unsigned short* __restrict__ codl,
    float* __restrict__ cnorm, int* __restrict__ counts, float* __restrict__ lsum)
{
    int i = blockIdx.x * 256 + threadIdx.x;
    const int Kc = (idxp[0] == 0) ? 512 : 1024;
    if (i < 2048) {                           // w1s [co][32], k=(kh*3+kw)*3+ci
        int co = i >> 5, k = i & 31;
        float v = 0.f;
        if (k < 27) {
            int khw = k / 3, ci = k - khw * 3;
            v = w1[(co * 3 + ci) * 9 + khw];
        }
        unsigned short h, l; split2(v, &h, &l);
        w1sh[i] = h; w1sl[i] = l; return;
    }
    i -= 2048;
    if (i < 73728) {                          // w2s [co][576], k=khw*64+ci
        int co = i / 576, k = i - co * 576;
        int khw = k >> 6, ci = k & 63;
        float v = w2[(co * 64 + ci) * 9 + khw];
        unsigned short h, l; split2(v, &h, &l);
        w2sh[i] = h; w2sl[i] = l; return;
    }
    i -= 73728;
    if (i < 294912) {                         // w3s [co][1152], k=khw*128+ci
        int co = i / 1152, k = i - co * 1152;
        int khw = k >> 7, ci = k & 127;
        float v = w3[(co * 128 + ci) * 9 + khw];
        unsigned short h, l; split2(v, &h, &l);
        w3sh[i] = h; w3sl[i] = l; return;
    }
    i -= 294912;
    if (i < 262144) {                         // codes [code][256]
        int code = i >> 8, c = i & 255;
        float v = 0.f;
        if (code < Kc) v = (code < 512) ? code0[code * 256 + c]
                                        : code1[(code - 512) * 256 + c];
        unsigned short h, l; split2(v, &h, &l);
        codh[i] = h; codl[i] = l; return;
    }
    i -= 262144;
    if (i < 1024) {                           // cnorm (exact fp32)
        float s;
        if (i < Kc) {
            const float* c = (i < 512) ? code0 + (size_t)i * 256
                                       : code1 + (size_t)(i - 512) * 256;
            s = 0.f;
            for (int k = 0; k < 256; ++k) s += c[k] * c[k];
        } else s = 3.0e38f;
        cnorm[i] = s; return;
    }
    i -= 1024;
    if (i < 1024) { counts[i] = 0; return; }
    i -= 1024;
    if (i == 0) lsum[0] = 0.f;
}

// ============================ conv12: fused conv1+conv2 (split-bf16 MFMA) ============================
__global__ __launch_bounds__(256, 2) void conv12_kernel(
    const float* __restrict__ x,
    const unsigned short* __restrict__ w1sh, const unsigned short* __restrict__ w1sl,
    const float* __restrict__ b1,
    const unsigned short* __restrict__ w2sh, const unsigned short* __restrict__ w2sl,
    const float* __restrict__ b2,
    unsigned short* __restrict__ y2h, unsigned short* __restrict__ y2l)
{
    __shared__ __align__(16) char smem[62496];
    float* xsp = (float*)smem;
    unsigned short* y1h = (unsigned short*)smem;
    unsigned short* y1l = (unsigned short*)(smem + 22032);
    unsigned short* Ah1 = (unsigned short*)(smem + 44064);
    unsigned short* Al1 = (unsigned short*)(smem + 53280);
    const int t = threadIdx.x;
    const int n = blockIdx.x >> 1, hh = blockIdx.x & 1;
    const int wv = t >> 6, lane = t & 63, lq = lane >> 4, lm = lane & 15;

    // ---- load x into padded LDS ----
    for (int i = t; i < 3468; i += 256) xsp[i] = 0.f;
    __syncthreads();
    const float* xn = x + (size_t)n * 3072;
    for (int i = t; i < 768; i += 256) {
        float4 v = ((const float4*)xn)[i];
        int ci = i >> 8, rem = i & 255, ih = rem >> 3, iw = (rem & 7) << 2;
        float* d = xsp + (size_t)(ci * 34 + ih + 1) * 34 + iw + 1;
        d[0] = v.x; d[1] = v.y; d[2] = v.z; d[3] = v.w;
    }
    __syncthreads();

    // ---- conv1 im2col ----
    for (int i = t; i < 4608; i += 256) {
        int px = i >> 5, k = i & 31;
        int l = px >> 4, ow = px & 15;
        float v = 0.f;
        if (k < 27 && !(hh == 0 && l == 0)) {
            int khw = k / 3, ci = k - khw * 3;
            int kh = khw / 3, kw = khw - kh * 3;
            int xr = 16 * hh - 2 + 2 * l + kh;      // padded row idx
            int xc = 2 * ow + kw;                   // padded col idx
            v = xsp[(size_t)(ci * 34 + xr) * 34 + xc];
        }
        unsigned short vh, vl; split2(v, &vh, &vl);
        int q = k >> 3, j = k & 7;
        Ah1[(q * 144 + px) * 8 + j] = vh;
        Al1[(q * 144 + px) * 8 + j] = vl;
    }
    __syncthreads();   // xsp dead; y1 region reusable

    // ---- zero y1 pads ----
    {
        unsigned* zh = (unsigned*)y1h; unsigned* zl = (unsigned*)y1l;
        for (int i = t; i < 612; i += 256) { zh[i] = 0u; zl[i] = 0u; }
        for (int i = t; i < 288; i += 256) {
            int l = 1 + i / 36, d = i - (l - 1) * 36;
            zh[l * 612 + d] = 0u; zl[l * 612 + d] = 0u;
        }
    }
    __syncthreads();

    // ---- conv1 via MFMA ----
    {
        f32x4 acc[9];
        #pragma unroll
        for (int mt = 0; mt < 9; ++mt) acc[mt] = (f32x4){0.f, 0.f, 0.f, 0.f};
        int co = wv * 16 + lm;
        bf16x8 bh = *(const bf16x8*)(w1sh + co * 32 + lq * 8);
        bf16x8 bl = *(const bf16x8*)(w1sl + co * 32 + lq * 8);
        #pragma unroll
        for (int mt = 0; mt < 9; ++mt) {
            bf16x8 ah = *(const bf16x8*)(Ah1 + (lq * 144 + mt * 16 + lm) * 8);
            bf16x8 al = *(const bf16x8*)(Al1 + (lq * 144 + mt * 16 + lm) * 8);
            acc[mt] = MFMA16(ah, bh, acc[mt]);
            acc[mt] = MFMA16(ah, bl, acc[mt]);
            acc[mt] = MFMA16(al, bh, acc[mt]);
        }
        float bias = b1[co];
        #pragma unroll
        for (int mt = 0; mt < 9; ++mt) {
            #pragma unroll
            for (int r = 0; r < 4; ++r) {
                int px = mt * 16 + lq * 4 + r;
                int l = px >> 4, ow = px & 15;
                if (hh == 0 && l == 0) continue;
                float v = fmaxf(acc[mt][r] + bias, 0.f);
                unsigned short vh, vl; split2(v, &vh, &vl);
                y1h[(l * 17 + ow + 1) * 72 + co] = vh;
                y1l[(l * 17 + ow + 1) * 72 + co] = vl;
            }
        }
    }
    __syncthreads();

    // ---- conv2 via MFMA ----
    {
        const int mt2 = wv >> 1, nh = wv & 1;
        f32x4 acc[4];
        #pragma unroll
        for (int i = 0; i < 4; ++i) acc[i] = (f32x4){0.f, 0.f, 0.f, 0.f};
        int px = mt2 * 16 + lm;
        int ohl = px >> 3, ow2 = px & 7;
        #pragma unroll
        for (int ks = 0; ks < 18; ++ks) {
            int khw = ks >> 1;
            int kh = khw / 3, kw = khw - kh * 3;
            int ci0 = (ks & 1) * 32 + lq * 8;
            int l = 2 * ohl + kh, c = 2 * ow2 + kw;
            bf16x8 ah = *(const bf16x8*)(y1h + (l * 17 + c) * 72 + ci0);
            bf16x8 al = *(const bf16x8*)(y1l + (l * 17 + c) * 72 + ci0);
            #pragma unroll
            for (int nt = 0; nt < 4; ++nt) {
                int co = nh * 64 + nt * 16 + lm;
                bf16x8 bh = *(const bf16x8*)(w2sh + co * 576 + ks * 32 + lq * 8);
                bf16x8 bl = *(const bf16x8*)(w2sl + co * 576 + ks * 32 + lq * 8);
                acc[nt] = MFMA16(ah, bh, acc[nt]);
                acc[nt] = MFMA16(ah, bl, acc[nt]);
                acc[nt] = MFMA16(al, bh, acc[nt]);
            }
        }
        #pragma unroll
        for (int nt = 0; nt < 4; ++nt) {
            int co = nh * 64 + nt * 16 + lm;
            float bias = b2[co];
            #pragma unroll
            for (int r = 0; r < 4; ++r) {
                int pxr = mt2 * 16 + lq * 4 + r;
                int ohr = pxr >> 3, owr = pxr & 7;
                float v = fmaxf(acc[nt][r] + bias, 0.f);
                unsigned short vh, vl; split2(v, &vh, &vl);
                size_t o = ((size_t)n * 64 + (hh * 4 + ohr) * 8 + owr) * 128 + co;
                y2h[o] = vh; y2l[o] = vl;
            }
        }
    }
}

// ============================ conv3: implicit GEMM 128px x 256co, K=1152 ============================
__global__ __launch_bounds__(256, 2) void conv3_kernel(
    const unsigned short* __restrict__ y2h, const unsigned short* __restrict__ y2l,
    const unsigned short* __restrict__ w3sh, const unsigned short* __restrict__ w3sl,
    const float* __restrict__ b3,
    unsigned short* __restrict__ fh, unsigned short* __restrict__ fl)
{
    __shared__ __align__(16) unsigned short Ah[4 * 128 * 8];   // [q][px][8]
    __shared__ __align__(16) unsigned short Al[4 * 128 * 8];
    const int t = threadIdx.x, b = blockIdx.x;
    const int wv = t >> 6, lane = t & 63, lq = lane >> 4, lm = lane & 15;
    const int mh = wv >> 1, nh = wv & 1;
    f32x4 acc[4][8];
    #pragma unroll
    for (int i = 0; i < 4; ++i)
        #pragma unroll
        for (int j = 0; j < 8; ++j) acc[i][j] = (f32x4){0.f, 0.f, 0.f, 0.f};
    const int gpx = t >> 1, gsel = t & 1;
    const int gimg = b * 8 + (gpx >> 4);
    const int gp = gpx & 15, goh = gp >> 2, gow = gp & 3;
    const unsigned short* gsrc = gsel ? y2l : y2h;
    unsigned short* gdst = gsel ? Al : Ah;

    for (int ks = 0; ks < 36; ++ks) {
        __syncthreads();
        {
            int khw = ks >> 2;
            int kh = khw / 3, kw = khw - kh * 3;
            int ci0 = (ks & 3) * 32;
            int ih = 2 * goh + kh - 1, iw = 2 * gow + kw - 1;
            if (ih >= 0 && ih < 8 && iw >= 0 && iw < 8) {
                const unsigned short* s = gsrc + ((size_t)gimg * 64 + ih * 8 + iw) * 128 + ci0;
                #pragma unroll
                for (int qq = 0; qq < 4; ++qq)
                    *(bf16x8*)(gdst + (qq * 128 + gpx) * 8) = *(const bf16x8*)(s + qq * 8);
            } else {
                #pragma unroll
                for (int qq = 0; qq < 4; ++qq)
                    *(bf16x8*)(gdst + (qq * 128 + gpx) * 8) = (bf16x8){0, 0, 0, 0, 0, 0, 0, 0};
            }
        }
        __syncthreads();
        bf16x8 ah[4], al[4];
        #pragma unroll
        for (int mt = 0; mt < 4; ++mt) {
            int mloc = mh * 64 + mt * 16 + lm;
            ah[mt] = *(const bf16x8*)(Ah + (lq * 128 + mloc) * 8);
            al[mt] = *(const bf16x8*)(Al + (lq * 128 + mloc) * 8);
        }
        #pragma unroll
        for (int nt = 0; nt < 8; ++nt) {
            int co = nh * 128 + nt * 16 + lm;
            bf16x8 bh = *(const bf16x8*)(w3sh + (size_t)co * 1152 + ks * 32 + lq * 8);
            bf16x8 bl = *(const bf16x8*)(w3sl + (size_t)co * 1152 + ks * 32 + lq * 8);
            #pragma unroll
            for (int mt = 0; mt < 4; ++mt) {
                acc[mt][nt] = MFMA16(ah[mt], bh, acc[mt][nt]);
                acc[mt][nt] = MFMA16(ah[mt], bl, acc[mt][nt]);
                acc[mt][nt] = MFMA16(al[mt], bh, acc[mt][nt]);
            }
        }
    }
    #pragma unroll
    for (int nt = 0; nt < 8; ++nt) {
        int co = nh * 128 + nt * 16 + lm;
        float bias = b3[co];
        #pragma unroll
        for (int mt = 0; mt < 4; ++mt) {
            #pragma unroll
            for (int r = 0; r < 4; ++r) {
                int mloc = mh * 64 + mt * 16 + lq * 4 + r;
                size_t row = (size_t)b * 128 + mloc;
                float v = fmaxf(acc[mt][nt][r] + bias, 0.f);
                unsigned short vh, vl; split2(v, &vh, &vl);
                fh[row * 256 + co] = vh;
                fl[row * 256 + co] = vl;
            }
        }
    }
}

// ============================ vq: fused distance GEMM + argmin + loss ============================
// ROUND 9: BARRIER-FREE per-wave-private-LDS sweep.
// Evidence: every ~650us variant (R0/R1/R4/R8) shares one element -- a
// barrier-synchronized chunk loop (waves advance in lockstep; every wave
// stalls on the same vmcnt+barrier drain simultaneously, so nothing hides
// anything; only 2 independent blocks/CU exist).  R6 (no barriers) was the
// outlier but had per-lane-divergent loads.  This version: zero
// __syncthreads; each wave owns a private 16KB LDS region and sweeps the
// 1024 codes in 64x16-code chunks -- R1's proven coalesced staging math
// (wave-linear global loads, swizzled ds_write) into its OWN buffer, then
// ds_read + 48 MFMAs.  All hazards are within-wave (compiler waitcnts).
// 8 fully independent wave-streams per CU overlap each other's latency.
// Epilogue = R6's verified register-norm + shuffle form.  Numerics and
// tie-breaking identical (ascending code order, strict <).
__global__ __launch_bounds__(256) void vq_kernel(
    const unsigned short* __restrict__ fh, const unsigned short* __restrict__ fl,
    const unsigned short* __restrict__ codh, const unsigned short* __restrict__ codl,
    const float* __restrict__ cnorm, int* __restrict__ enc,
    int* __restrict__ counts, float* __restrict__ lsum)
{
    __shared__ __align__(16) unsigned short Bh[4][4096];   // [wave][16 codes][256] swz
    __shared__ __align__(16) unsigned short Bl[4][4096];
    const int t = threadIdx.x;
    const int wv = t >> 6, lane = t & 63, lq = lane >> 4, lm = lane & 15;
    const int r0 = blockIdx.x * 128 + wv * 32;

    // ---- A fragments (32 rows, full K=256) in registers ----
    bf16x8 ah[2][8], al[2][8];
    #pragma unroll
    for (int mt = 0; mt < 2; ++mt)
        #pragma unroll
        for (int ks = 0; ks < 8; ++ks) {
            size_t base = ((size_t)(r0 + mt * 16 + lm)) * 256 + ks * 32 + lq * 8;
            ah[mt][ks] = *(const bf16x8*)(fh + base);
            al[mt][ks] = *(const bf16x8*)(fl + base);
        }
    // ||f||^2 for row (mt*16+lm): after the reduce every lane holds its row's norm
    float nrm[2];
    #pragma unroll
    for (int mt = 0; mt < 2; ++mt) {
        float s = 0.f;
        #pragma unroll
        for (int ks = 0; ks < 8; ++ks)
            #pragma unroll
            for (int j = 0; j < 8; ++j) {
                float v = bf16_to_f((unsigned short)ah[mt][ks][j]) +
                          bf16_to_f((unsigned short)al[mt][ks][j]);
                s += v * v;
            }
        s += __shfl_xor(s, 16);
        s += __shfl_xor(s, 32);
        nrm[mt] = s;
    }

    // ---- per-lane staging offsets (granule g = i*64 + lane of a 16x32 chunk) ----
    // LDS short-offset(row,slot) = row*256 + ((slot ^ (row&7)) << 3)
    int stoff[8];
    #pragma unroll
    for (int i = 0; i < 8; ++i) {
        int g = i * 64 + lane;
        int row = g >> 5, slot = g & 31;
        stoff[i] = row * 256 + ((slot ^ (row & 7)) << 3);
    }
    const float4* gh = (const float4*)codh;   // 16B granules, [code][slot] linear
    const float4* gl = (const float4*)codl;
    unsigned short* bhw = &Bh[wv][0];
    unsigned short* blw = &Bl[wv][0];
    const int cx = lm & 7;
    const int cb = lm * 256;

    float bv[2][4]; int bi[2][4];
    #pragma unroll
    for (int mt = 0; mt < 2; ++mt)
        #pragma unroll
        for (int r = 0; r < 4; ++r) { bv[mt][r] = 3.0e38f; bi[mt][r] = 0; }

    for (int ch = 0; ch < 64; ++ch) {
        // ---- stage this wave's 16-code chunk (2 batches of 4h+4l granules) ----
        {
            float4 sgh[4], sgl[4];
            #pragma unroll
            for (int i = 0; i < 4; ++i) {
                int u = ch * 512 + i * 64 + lane;
                sgh[i] = gh[u];
                sgl[i] = gl[u];
            }
            #pragma unroll
            for (int i = 0; i < 4; ++i) {
                *(float4*)(&bhw[stoff[i]]) = sgh[i];
                *(float4*)(&blw[stoff[i]]) = sgl[i];
            }
            #pragma unroll
            for (int i = 0; i < 4; ++i) {
                int u = ch * 512 + (i + 4) * 64 + lane;
                sgh[i] = gh[u];
                sgl[i] = gl[u];
            }
            #pragma unroll
            for (int i = 0; i < 4; ++i) {
                *(float4*)(&bhw[stoff[i + 4]]) = sgh[i];
                *(float4*)(&blw[stoff[i + 4]]) = sgl[i];
            }
        }
        // ---- compute: 16 codes x 32 rows (compiler orders ds_write->ds_read) ----
        f32x4 acc0 = (f32x4){0.f, 0.f, 0.f, 0.f};
        f32x4 acc1 = (f32x4){0.f, 0.f, 0.f, 0.f};
        #pragma unroll
        for (int ks = 0; ks < 8; ++ks) {
            int off = cb + (((ks * 4 + lq) ^ cx) << 3);
            bf16x8 bh = *(const bf16x8*)(&bhw[off]);
            bf16x8 bl = *(const bf16x8*)(&blw[off]);
            acc0 = MFMA16(ah[0][ks], bh, acc0);
            acc1 = MFMA16(ah[1][ks], bh, acc1);
            acc0 = MFMA16(ah[0][ks], bl, acc0);
            acc1 = MFMA16(ah[1][ks], bl, acc1);
            acc0 = MFMA16(al[0][ks], bh, acc0);
            acc1 = MFMA16(al[1][ks], bh, acc1);
        }
        int code = ch * 16 + lm;
        float cn = cnorm[code];
        #pragma unroll
        for (int r = 0; r < 4; ++r) {
            float d0 = cn - 2.f * acc0[r];
            if (d0 < bv[0][r]) { bv[0][r] = d0; bi[0][r] = code; }
            float d1 = cn - 2.f * acc1[r];
            if (d1 < bv[1][r]) { bv[1][r] = d1; bi[1][r] = code; }
        }
    }

    // ---- reduce over the 16 code-lanes (lexicographic: value, then index) ----
    #pragma unroll
    for (int mt = 0; mt < 2; ++mt)
        #pragma unroll
        for (int r = 0; r < 4; ++r) {
            float v = bv[mt][r]; int i = bi[mt][r];
            #pragma unroll
            for (int mask = 1; mask <= 8; mask <<= 1) {
                float ov = __shfl_xor(v, mask);
                int oi = __shfl_xor(i, mask);
                if (ov < v || (ov == v && oi < i)) { v = ov; i = oi; }
            }
            bv[mt][r] = v; bi[mt][r] = i;
        }
    // gather norms of rows (mt*16 + lq*4 + r) -- uniform shuffles, all lanes
    float fnr[2][4];
    #pragma unroll
    for (int mt = 0; mt < 2; ++mt)
        #pragma unroll
        for (int r = 0; r < 4; ++r)
            fnr[mt][r] = __shfl(nrm[mt], lq * 4 + r);

    float lp = 0.f;
    if (lm == 0) {   // lanes 0,16,32,48: rows mt*16 + lq*4 + r
        #pragma unroll
        for (int mt = 0; mt < 2; ++mt)
            #pragma unroll
            for (int r = 0; r < 4; ++r) {
                int row_loc = mt * 16 + lq * 4 + r;
                enc[r0 + row_loc] = bi[mt][r];
                atomicAdd(&counts[bi[mt][r]], 1);
                lp += fnr[mt][r] + bv[mt][r];
            }
    }
    lp += __shfl_xor(lp, 16);
    lp += __shfl_xor(lp, 32);
    if (lane == 0) atomicAdd(lsum, lp);
}

// ============================ prep2: fc1 weight slices split ============================
// f1s[pos][out][c] = fc1w[out][c*16+pos]
__global__ __launch_bounds__(256) void prep2_kernel(
    const float* __restrict__ fc1w,
    unsigned short* __restrict__ f1h, unsigned short* __restrict__ f1l)
{
    int i = blockIdx.x * 256 + threadIdx.x;   // 2,097,152
    int pos = i >> 17, rem = i & 131071, o = rem >> 8, c = rem & 255;
    float v = fc1w[(size_t)o * 4096 + c * 16 + pos];
    unsigned short h, l; split2(v, &h, &l);
    f1h[i] = h; f1l[i] = l;
}

// ============================ lut: LUT[pos][code][out] = codes . W1-slice ============================
__global__ __launch_bounds__(256, 2) void lut_kernel(
    const unsigned short* __restrict__ codh, const unsigned short* __restrict__ codl,
    const unsigned short* __restrict__ f1h, const unsigned short* __restrict__ f1l,
    float* __restrict__ lut)
{
    const int t = threadIdx.x, b = blockIdx.x;
    const int pos = b >> 5, sub = b & 31, mblk = sub >> 2, nblk = sub & 3;
    const int wv = t >> 6, lane = t & 63, lq = lane >> 4, lm = lane & 15;
    const int mh = wv >> 1, nh = wv & 1;
    f32x4 acc[4][4];
    #pragma unroll
    for (int i = 0; i < 4; ++i)
        #pragma unroll
        for (int j = 0; j < 4; ++j) acc[i][j] = (f32x4){0.f, 0.f, 0.f, 0.f};
    #pragma unroll
    for (int ks = 0; ks < 8; ++ks) {
        bf16x8 ah[4], al[4];
        #pragma unroll
        for (int mt = 0; mt < 4; ++mt) {
            int code = mblk * 128 + mh * 64 + mt * 16 + lm;
            ah[mt] = *(const bf16x8*)(codh + (size_t)code * 256 + ks * 32 + lq * 8);
            al[mt] = *(const bf16x8*)(codl + (size_t)code * 256 + ks * 32 + lq * 8);
        }
        #pragma unroll
        for (int nt = 0; nt < 4; ++nt) {
            int o = nblk * 128 + nh * 64 + nt * 16 + lm;
            bf16x8 bh = *(const bf16x8*)(f1h + ((size_t)pos * 512 + o) * 256 + ks * 32 + lq * 8);
            bf16x8 bl = *(const bf16x8*)(f1l + ((size_t)pos * 512 + o) * 256 + ks * 32 + lq * 8);
            #pragma unroll
            for (int mt = 0; mt < 4; ++mt) {
                acc[mt][nt] = MFMA16(ah[mt], bh, acc[mt][nt]);
                acc[mt][nt] = MFMA16(ah[mt], bl, acc[mt][nt]);
                acc[mt][nt] = MFMA16(al[mt], bh, acc[mt][nt]);
            }
        }
    }
    #pragma unroll
    for (int nt = 0; nt < 4; ++nt) {
        int o = nblk * 128 + nh * 64 + nt * 16 + lm;
        #pragma unroll
        for (int mt = 0; mt < 4; ++mt)
            #pragma unroll
            for (int r = 0; r < 4; ++r) {
                int code = mblk * 128 + mh * 64 + mt * 16 + lq * 4 + r;
                lut[((size_t)pos * 1024 + code) * 512 + o] = acc[mt][nt][r];
            }
    }
}

// ============================ hsum: h = gelu(b1 + sum_pos LUT[pos][enc]) ============================
__device__ inline float gelu_tanh(float x) {
    float x3 = x * x * x;
    float u = 0.7978845608028654f * (x + 0.044715f * x3);
    return 0.5f * x * (1.0f + tanhf(u));
}

__global__ __launch_bounds__(256) void hsum_kernel(
    const int* __restrict__ enc, const float* __restrict__ lut,
    const float* __restrict__ fc1b, float* __restrict__ h)
{
    __shared__ int e[16];
    const int t = threadIdx.x, img = blockIdx.x;
    if (t < 16) e[t] = enc[img * 16 + t];
    __syncthreads();
    for (int rep = 0; rep < 2; ++rep) {
        int o = rep * 256 + t;
        float acc = fc1b[o];
        #pragma unroll
        for (int p = 0; p < 16; ++p)
            acc += lut[((size_t)p * 1024 + e[p]) * 512 + o];
        h[(size_t)img * 512 + o] = gelu_tanh(acc);
    }
}

// ============================ fc2 ============================
__global__ __launch_bounds__(256) void fc2_kernel(
    const float* __restrict__ h, const float* __restrict__ fc2w,
    const float* __restrict__ fc2b, float* __restrict__ out)
{
    __shared__ float ws2[10 * 512];
    const int t = threadIdx.x;
    for (int i = t; i < 5120; i += 256) ws2[i] = fc2w[i];
    __syncthreads();
    const int lane = t & 63, wv = t >> 6;
    const int n = blockIdx.x * 4 + wv;
    float acc[10];
    #pragma unroll
    for (int j = 0; j < 10; ++j) acc[j] = 0.f;
    #pragma unroll
    for (int i = 0; i < 8; ++i) {
        float hv = h[(size_t)n * 512 + lane + 64 * i];
        #pragma unroll
        for (int j = 0; j < 10; ++j) acc[j] += hv * ws2[j * 512 + lane + 64 * i];
    }
    #pragma unroll
    for (int j = 0; j < 10; ++j) {
        float v = acc[j];
        for (int off = 32; off; off >>= 1) v += __shfl_down(v, off);
        if (lane == 0) out[(size_t)n * 10 + j] = v + fc2b[j];
    }
}

// ============================ finalize ============================
__global__ __launch_bounds__(256) void finalize_kernel(
    const int* __restrict__ counts, const float* __restrict__ lsum,
    const int* __restrict__ idxp, float* __restrict__ out)
{
    __shared__ float red[256];
    const int t = threadIdx.x;
    const int Kc = (idxp[0] == 0) ? 512 : 1024;
    float s = 0.f;
    for (int k = t; k < Kc; k += 256) {
        float p = (float)counts[k] * (1.0f / 65536.0f);
        s += p * logf(p + 1e-10f);
    }
    red[t] = s;
    __syncthreads();
    for (int o = 128; o; o >>= 1) {
        if (t < o) red[t] += red[t + o];
        __syncthreads();
    }
    if (t == 0) {
        out[40960] = lsum[0] * (1.25f / 16777216.0f);   // (1+0.25) * mean over 65536*256
        out[40961] = expf(-red[0]);
    }
}

// ============================ launch ============================
extern "C" void kernel_launch(void* const* d_in, const int* in_sizes, int n_in,
                              void* d_out, int out_size, void* d_ws, size_t ws_size,
                              hipStream_t stream)
{
    const float* x     = (const float*)d_in[0];
    const float* w1    = (const float*)d_in[1];
    const float* b1    = (const float*)d_in[2];
    const float* w2    = (const float*)d_in[3];
    const float* b2    = (const float*)d_in[4];
    const float* w3    = (const float*)d_in[5];
    const float* b3    = (const float*)d_in[6];
    const float* code0 = (const float*)d_in[7];
    const float* code1 = (const float*)d_in[8];
    const float* fc1w  = (const float*)d_in[9];
    const float* fc1b  = (const float*)d_in[10];
    const float* fc2w  = (const float*)d_in[11];
    const float* fc2b  = (const float*)d_in[12];
    const int*   idxp  = (const int*)d_in[13];
    float* out = (float*)d_out;
    char* ws = (char*)d_ws;

    unsigned short* w1sh = (unsigned short*)(ws + OFF_W1SH);
    unsigned short* w1sl = (unsigned short*)(ws + OFF_W1SL);
    unsigned short* w2sh = (unsigned short*)(ws + OFF_W2SH);
    unsigned short* w2sl = (unsigned short*)(ws + OFF_W2SL);
    unsigned short* w3sh = (unsigned short*)(ws + OFF_W3SH);
    unsigned short* w3sl = (unsigned short*)(ws + OFF_W3SL);
    unsigned short* codh = (unsigned short*)(ws + OFF_CODH);
    unsigned short* codl = (unsigned short*)(ws + OFF_CODL);
    float* cnorm = (float*)(ws + OFF_CNORM);
    int*   counts= (int*)(ws + OFF_COUNTS);
    float* lsum  = (float*)(ws + OFF_LOSS);
    int*   enc   = (int*)(ws + OFF_ENC);
    unsigned short* y2h = (unsigned short*)(ws + OFF_BIG);
    unsigned short* y2l = (unsigned short*)(ws + OFF_BIG + 67108864);
    unsigned short* fh  = (unsigned short*)(ws + OFF_FLATS);
    unsigned short* fl  = (unsigned short*)(ws + OFF_FLATS + 33554432);
    // post-conv3 aliases (y2 region dead):
    float* lut = (float*)(ws + OFF_BIG);
    float* h   = (float*)(ws + OFF_BIG + 33554432);
    // post-vq aliases (flat region dead):
    unsigned short* f1h = (unsigned short*)(ws + OFF_FLATS);
    unsigned short* f1l = (unsigned short*)(ws + OFF_FLATS + 4194304);

    prep1_kernel<<<2481, 256, 0, stream>>>(w1, w2, w3, code0, code1, idxp,
                                           w1sh, w1sl, w2sh, w2sl, w3sh, w3sl,
                                           codh, codl, cnorm, counts, lsum);
    conv12_kernel<<<8192, 256, 0, stream>>>(x, w1sh, w1sl, b1, w2sh, w2sl, b2, y2h, y2l);
    conv3_kernel<<<512, 256, 0, stream>>>(y2h, y2l, w3sh, w3sl, b3, fh, fl);
    vq_kernel<<<512, 256, 0, stream>>>(fh, fl, codh, codl, cnorm, enc, counts, lsum);
    prep2_kernel<<<8192, 256, 0, stream>>>(fc1w, f1h, f1l);
    lut_kernel<<<512, 256, 0, stream>>>(codh, codl, f1h, f1l, lut);
    hsum_kernel<<<4096, 256, 0, stream>>>(enc, lut, fc1b, h);
    fc2_kernel<<<1024, 256, 0, stream>>>(h, fc2w, fc2b, out);
    finalize_kernel<<<1, 256, 0, stream>>>(counts, lsum, idxp, out);
}

// Round 10
// 1650.952 us; speedup vs baseline: 1.1153x; 1.1153x over previous
//
#include <hip/hip_runtime.h>
#include <math.h>

// ============================ MFMA types/helpers ============================
typedef short bf16x8 __attribute__((ext_vector_type(8)));   // 8 bf16 (4 VGPRs)
typedef float f32x4 __attribute__((ext_vector_type(4)));
typedef float f32x16 __attribute__((ext_vector_type(16)));

#define MFMA16(a, b, c) __builtin_amdgcn_mfma_f32_16x16x32_bf16((a), (b), (c), 0, 0, 0)
#define MFMA32(a, b, c) __builtin_amdgcn_mfma_f32_32x32x16_bf16((a), (b), (c), 0, 0, 0)

__device__ inline unsigned short bf16_rn(float x) {
    unsigned u = __float_as_uint(x);
    unsigned r = u + 0x7FFFu + ((u >> 16) & 1u);
    return (unsigned short)(r >> 16);
}
__device__ inline float bf16_to_f(unsigned short h) {
    return __uint_as_float(((unsigned)h) << 16);
}
__device__ inline void split2(float x, unsigned short* hp, unsigned short* lp) {
    unsigned short h = bf16_rn(x);
    *hp = h;
    *lp = bf16_rn(x - bf16_to_f(h));
}

// ============================ workspace layout (bytes) ============================
static constexpr size_t OFF_W1SH  = 0;           // [64co][32k] shorts  (k 27..31 zero)
static constexpr size_t OFF_W1SL  = 4096;
static constexpr size_t OFF_W2SH  = 8192;        // [128co][576k] shorts, k = khw*64+ci
static constexpr size_t OFF_W2SL  = 155648;
static constexpr size_t OFF_W3SH  = 303104;      // [256co][1152k] shorts, k = khw*128+ci
static constexpr size_t OFF_W3SL  = 892928;
static constexpr size_t OFF_CODH  = 1482752;     // [1024][256] shorts (rows>=Kc zero)
static constexpr size_t OFF_CODL  = 2007040;
static constexpr size_t OFF_CNORM = 2531328;     // [1024] f32 (3e38 for >=Kc)
static constexpr size_t OFF_COUNTS= 2535424;     // [1024] int
static constexpr size_t OFF_LOSS  = 2539520;     // f32
static constexpr size_t OFF_ENC   = 2539776;     // [65536] int
static constexpr size_t OFF_BIG   = 2801920;     // y2h(67108864)+y2l(67108864)
                                                 // post-conv3 reuse: LUT f32 (33554432) + h f32 (8388608)
static constexpr size_t OFF_FLATS = 137019648;   // fh(33554432)+fl(33554432)
                                                 // post-vq reuse: fc1wsh(4194304)+fc1wsl(4194304)

// ============================ prep1: weight/code splits ============================
__global__ __launch_bounds__(256) void prep1_kernel(
    const float* __restrict__ w1, const float* __restrict__ w2,
    const float* __restrict__ w3, const float* __restrict__ code0,
    const float* __restrict__ code1, const int* __restrict__ idxp,
    unsigned short* __restrict__ w1sh, unsigned short* __restrict__ w1sl,
    unsigned short* __restrict__ w2sh, unsigned short* __restrict__ w2sl,
    unsigned short* __restrict__ w3sh, unsigned short* __restrict__ w3sl,
    unsigned short* __restrict__ codh, unsigned short* __restrict__ codl,
    float* __restrict__ cnorm, int* __restrict__ counts, float* __restrict__ lsum)
{
    int i = blockIdx.x * 256 + threadIdx.x;
    const int Kc = (idxp[0] == 0) ? 512 : 1024;
    if (i < 2048) {                           // w1s [co][32], k=(kh*3+kw)*3+ci
        int co = i >> 5, k = i & 31;
        float v = 0.f;
        if (k < 27) {
            int khw = k / 3, ci = k - khw * 3;
            v = w1[(co * 3 + ci) * 9 + khw];
        }
        unsigned short h, l; split2(v, &h, &l);
        w1sh[i] = h; w1sl[i] = l; return;
    }
    i -= 2048;
    if (i < 73728) {                          // w2s [co][576], k=khw*64+ci
        int co = i / 576, k = i - co * 576;
        int khw = k >> 6, ci = k & 63;
        float v = w2[(co * 64 + ci) * 9 + khw];
        unsigned short h, l; split2(v, &h, &l);
        w2sh[i] = h; w2sl[i] = l; return;
    }
    i -= 73728;
    if (i < 294912) {                         // w3s [co][1152], k=khw*128+ci
        int co = i / 1152, k = i - co * 1152;
        int khw = k >> 7, ci = k & 127;
        float v = w3[(co * 128 + ci) * 9 + khw];
        unsigned short h, l; split2(v, &h, &l);
        w3sh[i] = h; w3sl[i] = l; return;
    }
    i -= 294912;
    if (i < 262144) {                         // codes [code][256]
        int code = i >> 8, c = i & 255;
        float v = 0.f;
        if (code < Kc) v = (code < 512) ? code0[code * 256 + c]
                                        : code1[(code - 512) * 256 + c];
        unsigned short h, l; split2(v, &h, &l);
        codh[i] = h; codl[i] = l; return;
    }
    i -= 262144;
    if (i < 1024) {                           // cnorm (exact fp32)
        float s;
        if (i < Kc) {
            const float* c = (i < 512) ? code0 + (size_t)i * 256
                                       : code1 + (size_t)(i - 512) * 256;
            s = 0.f;
            for (int k = 0; k < 256; ++k) s += c[k] * c[k];
        } else s = 3.0e38f;
        cnorm[i] = s; return;
    }
    i -= 1024;
    if (i < 1024) { counts[i] = 0; return; }
    i -= 1024;
    if (i == 0) lsum[0] = 0.f;
}

// ============================ conv12: fused conv1+conv2 (split-bf16 MFMA) ============================
__global__ __launch_bounds__(256, 2) void conv12_kernel(
    const float* __restrict__ x,
    const unsigned short* __restrict__ w1sh, const unsigned short* __restrict__ w1sl,
    const float* __restrict__ b1,
    const unsigned short* __restrict__ w2sh, const unsigned short* __restrict__ w2sl,
    const float* __restrict__ b2,
    unsigned short* __restrict__ y2h, unsigned short* __restrict__ y2l)
{
    __shared__ __align__(16) char smem[62496];
    float* xsp = (float*)smem;
    unsigned short* y1h = (unsigned short*)smem;
    unsigned short* y1l = (unsigned short*)(smem + 22032);
    unsigned short* Ah1 = (unsigned short*)(smem + 44064);
    unsigned short* Al1 = (unsigned short*)(smem + 53280);
    const int t = threadIdx.x;
    const int n = blockIdx.x >> 1, hh = blockIdx.x & 1;
    const int wv = t >> 6, lane = t & 63, lq = lane >> 4, lm = lane & 15;

    // ---- load x into padded LDS ----
    for (int i = t; i < 3468; i += 256) xsp[i] = 0.f;
    __syncthreads();
    const float* xn = x + (size_t)n * 3072;
    for (int i = t; i < 768; i += 256) {
        float4 v = ((const float4*)xn)[i];
        int ci = i >> 8, rem = i & 255, ih = rem >> 3, iw = (rem & 7) << 2;
        float* d = xsp + (size_t)(ci * 34 + ih + 1) * 34 + iw + 1;
        d[0] = v.x; d[1] = v.y; d[2] = v.z; d[3] = v.w;
    }
    __syncthreads();

    // ---- conv1 im2col ----
    for (int i = t; i < 4608; i += 256) {
        int px = i >> 5, k = i & 31;
        int l = px >> 4, ow = px & 15;
        float v = 0.f;
        if (k < 27 && !(hh == 0 && l == 0)) {
            int khw = k / 3, ci = k - khw * 3;
            int kh = khw / 3, kw = khw - kh * 3;
            int xr = 16 * hh - 2 + 2 * l + kh;      // padded row idx
            int xc = 2 * ow + kw;                   // padded col idx
            v = xsp[(size_t)(ci * 34 + xr) * 34 + xc];
        }
        unsigned short vh, vl; split2(v, &vh, &vl);
        int q = k >> 3, j = k & 7;
        Ah1[(q * 144 + px) * 8 + j] = vh;
        Al1[(q * 144 + px) * 8 + j] = vl;
    }
    __syncthreads();   // xsp dead; y1 region reusable

    // ---- zero y1 pads ----
    {
        unsigned* zh = (unsigned*)y1h; unsigned* zl = (unsigned*)y1l;
        for (int i = t; i < 612; i += 256) { zh[i] = 0u; zl[i] = 0u; }
        for (int i = t; i < 288; i += 256) {
            int l = 1 + i / 36, d = i - (l - 1) * 36;
            zh[l * 612 + d] = 0u; zl[l * 612 + d] = 0u;
        }
    }
    __syncthreads();

    // ---- conv1 via MFMA ----
    {
        f32x4 acc[9];
        #pragma unroll
        for (int mt = 0; mt < 9; ++mt) acc[mt] = (f32x4){0.f, 0.f, 0.f, 0.f};
        int co = wv * 16 + lm;
        bf16x8 bh = *(const bf16x8*)(w1sh + co * 32 + lq * 8);
        bf16x8 bl = *(const bf16x8*)(w1sl + co * 32 + lq * 8);
        #pragma unroll
        for (int mt = 0; mt < 9; ++mt) {
            bf16x8 ah = *(const bf16x8*)(Ah1 + (lq * 144 + mt * 16 + lm) * 8);
            bf16x8 al = *(const bf16x8*)(Al1 + (lq * 144 + mt * 16 + lm) * 8);
            acc[mt] = MFMA16(ah, bh, acc[mt]);
            acc[mt] = MFMA16(ah, bl, acc[mt]);
            acc[mt] = MFMA16(al, bh, acc[mt]);
        }
        float bias = b1[co];
        #pragma unroll
        for (int mt = 0; mt < 9; ++mt) {
            #pragma unroll
            for (int r = 0; r < 4; ++r) {
                int px = mt * 16 + lq * 4 + r;
                int l = px >> 4, ow = px & 15;
                if (hh == 0 && l == 0) continue;
                float v = fmaxf(acc[mt][r] + bias, 0.f);
                unsigned short vh, vl; split2(v, &vh, &vl);
                y1h[(l * 17 + ow + 1) * 72 + co] = vh;
                y1l[(l * 17 + ow + 1) * 72 + co] = vl;
            }
        }
    }
    __syncthreads();

    // ---- conv2 via MFMA ----
    {
        const int mt2 = wv >> 1, nh = wv & 1;
        f32x4 acc[4];
        #pragma unroll
        for (int i = 0; i < 4; ++i) acc[i] = (f32x4){0.f, 0.f, 0.f, 0.f};
        int px = mt2 * 16 + lm;
        int ohl = px >> 3, ow2 = px & 7;
        #pragma unroll
        for (int ks = 0; ks < 18; ++ks) {
            int khw = ks >> 1;
            int kh = khw / 3, kw = khw - kh * 3;
            int ci0 = (ks & 1) * 32 + lq * 8;
            int l = 2 * ohl + kh, c = 2 * ow2 + kw;
            bf16x8 ah = *(const bf16x8*)(y1h + (l * 17 + c) * 72 + ci0);
            bf16x8 al = *(const bf16x8*)(y1l + (l * 17 + c) * 72 + ci0);
            #pragma unroll
            for (int nt = 0; nt < 4; ++nt) {
                int co = nh * 64 + nt * 16 + lm;
                bf16x8 bh = *(const bf16x8*)(w2sh + co * 576 + ks * 32 + lq * 8);
                bf16x8 bl = *(const bf16x8*)(w2sl + co * 576 + ks * 32 + lq * 8);
                acc[nt] = MFMA16(ah, bh, acc[nt]);
                acc[nt] = MFMA16(ah, bl, acc[nt]);
                acc[nt] = MFMA16(al, bh, acc[nt]);
            }
        }
        #pragma unroll
        for (int nt = 0; nt < 4; ++nt) {
            int co = nh * 64 + nt * 16 + lm;
            float bias = b2[co];
            #pragma unroll
            for (int r = 0; r < 4; ++r) {
                int pxr = mt2 * 16 + lq * 4 + r;
                int ohr = pxr >> 3, owr = pxr & 7;
                float v = fmaxf(acc[nt][r] + bias, 0.f);
                unsigned short vh, vl; split2(v, &vh, &vl);
                size_t o = ((size_t)n * 64 + (hh * 4 + ohr) * 8 + owr) * 128 + co;
                y2h[o] = vh; y2l[o] = vl;
            }
        }
    }
}

// ============================ conv3: implicit GEMM 128px x 256co, K=1152 ============================
__global__ __launch_bounds__(256, 2) void conv3_kernel(
    const unsigned short* __restrict__ y2h, const unsigned short* __restrict__ y2l,
    const unsigned short* __restrict__ w3sh, const unsigned short* __restrict__ w3sl,
    const float* __restrict__ b3,
    unsigned short* __restrict__ fh, unsigned short* __restrict__ fl)
{
    __shared__ __align__(16) unsigned short Ah[4 * 128 * 8];   // [q][px][8]
    __shared__ __align__(16) unsigned short Al[4 * 128 * 8];
    const int t = threadIdx.x, b = blockIdx.x;
    const int wv = t >> 6, lane = t & 63, lq = lane >> 4, lm = lane & 15;
    const int mh = wv >> 1, nh = wv & 1;
    f32x4 acc[4][8];
    #pragma unroll
    for (int i = 0; i < 4; ++i)
        #pragma unroll
        for (int j = 0; j < 8; ++j) acc[i][j] = (f32x4){0.f, 0.f, 0.f, 0.f};
    const int gpx = t >> 1, gsel = t & 1;
    const int gimg = b * 8 + (gpx >> 4);
    const int gp = gpx & 15, goh = gp >> 2, gow = gp & 3;
    const unsigned short* gsrc = gsel ? y2l : y2h;
    unsigned short* gdst = gsel ? Al : Ah;

    for (int ks = 0; ks < 36; ++ks) {
        __syncthreads();
        {
            int khw = ks >> 2;
            int kh = khw / 3, kw = khw - kh * 3;
            int ci0 = (ks & 3) * 32;
            int ih = 2 * goh + kh - 1, iw = 2 * gow + kw - 1;
            if (ih >= 0 && ih < 8 && iw >= 0 && iw < 8) {
                const unsigned short* s = gsrc + ((size_t)gimg * 64 + ih * 8 + iw) * 128 + ci0;
                #pragma unroll
                for (int qq = 0; qq < 4; ++qq)
                    *(bf16x8*)(gdst + (qq * 128 + gpx) * 8) = *(const bf16x8*)(s + qq * 8);
            } else {
                #pragma unroll
                for (int qq = 0; qq < 4; ++qq)
                    *(bf16x8*)(gdst + (qq * 128 + gpx) * 8) = (bf16x8){0, 0, 0, 0, 0, 0, 0, 0};
            }
        }
        __syncthreads();
        bf16x8 ah[4], al[4];
        #pragma unroll
        for (int mt = 0; mt < 4; ++mt) {
            int mloc = mh * 64 + mt * 16 + lm;
            ah[mt] = *(const bf16x8*)(Ah + (lq * 128 + mloc) * 8);
            al[mt] = *(const bf16x8*)(Al + (lq * 128 + mloc) * 8);
        }
        #pragma unroll
        for (int nt = 0; nt < 8; ++nt) {
            int co = nh * 128 + nt * 16 + lm;
            bf16x8 bh = *(const bf16x8*)(w3sh + (size_t)co * 1152 + ks * 32 + lq * 8);
            bf16x8 bl = *(const bf16x8*)(w3sl + (size_t)co * 1152 + ks * 32 + lq * 8);
            #pragma unroll
            for (int mt = 0; mt < 4; ++mt) {
                acc[mt][nt] = MFMA16(ah[mt], bh, acc[mt][nt]);
                acc[mt][nt] = MFMA16(ah[mt], bl, acc[mt][nt]);
                acc[mt][nt] = MFMA16(al[mt], bh, acc[mt][nt]);
            }
        }
    }
    #pragma unroll
    for (int nt = 0; nt < 8; ++nt) {
        int co = nh * 128 + nt * 16 + lm;
        float bias = b3[co];
        #pragma unroll
        for (int mt = 0; mt < 4; ++mt) {
            #pragma unroll
            for (int r = 0; r < 4; ++r) {
                int mloc = mh * 64 + mt * 16 + lq * 4 + r;
                size_t row = (size_t)b * 128 + mloc;
                float v = fmaxf(acc[mt][nt][r] + bias, 0.f);
                unsigned short vh, vl; split2(v, &vh, &vl);
                fh[row * 256 + co] = vh;
                fl[row * 256 + co] = vl;
            }
        }
    }
}

// ============================ vq: fused distance GEMM + argmin + loss ============================
// ROUND 10: R1's dbuf structure (fastest family, 642us) with 32x32x16 MFMA.
// Evidence: 6 structures pinned at 642-875us; effective rate ~158 TF =
// ~64 cyc/MFMA with all pipes reading idle -> per-INSTRUCTION cost wall.
// Nothing varied instruction count so far. This version halves MFMA count
// (3072->1536/wave, 2x FLOP/instr) and cuts total instrs ~33%, keeping
// R1's staging/dbuf/barrier code verbatim. Split-triple becomes 3
// INDEPENDENT acc chains (P=ah*bh, Q=ah*bl, R=al*bh) summed in the
// epilogue (f32 adds commute into d = cn - 2*(P+Q+R): same math).
// C layout (HW-verified m74/m101): col=lane&31, row=(reg&3)+8*(reg>>2)
// +4*(lane>>5). A/B: row(col)=lane&31, k=(lane>>5)*8+j.
// Tie-break preserved: ascending chunk order, strict <, lexicographic
// butterfly over the 32-lane code groups.
__global__ __launch_bounds__(256, 2) void vq_kernel(
    const unsigned short* __restrict__ fh, const unsigned short* __restrict__ fl,
    const unsigned short* __restrict__ codh, const unsigned short* __restrict__ codl,
    const float* __restrict__ cnorm, int* __restrict__ enc,
    int* __restrict__ counts, float* __restrict__ lsum)
{
    __shared__ __align__(16) unsigned short Bh[2][8192];   // [buf][code(32)][swz slot(32)*8]
    __shared__ __align__(16) unsigned short Bl[2][8192];
    const int t = threadIdx.x;
    const int wv = t >> 6, lane = t & 63;
    const int lr = lane & 31;        // A-row / B-col within 32-tile
    const int lh = lane >> 5;        // k-half selector
    const int r0 = blockIdx.x * 128 + wv * 32;

    // ---- A fragments: 16 k-steps of 16, lane holds row lr, k=ks*16+lh*8+j ----
    bf16x8 ah[16], al[16];
    #pragma unroll
    for (int ks = 0; ks < 16; ++ks) {
        size_t base = (size_t)(r0 + lr) * 256 + ks * 16 + lh * 8;
        ah[ks] = *(const bf16x8*)(fh + base);
        al[ks] = *(const bf16x8*)(fl + base);
    }
    // ||f||^2 of row lr: per-lane covers half the k; xor-32 completes it
    float nrm = 0.f;
    #pragma unroll
    for (int ks = 0; ks < 16; ++ks)
        #pragma unroll
        for (int j = 0; j < 8; ++j) {
            float v = bf16_to_f((unsigned short)ah[ks][j]) +
                      bf16_to_f((unsigned short)al[ks][j]);
            nrm += v * v;
        }
    nrm += __shfl_xor(nrm, 32);

    // ---- staging offsets (VERBATIM R1): granule u = uu*256+t of 32x256 chunk ----
    int stoff[4];
    #pragma unroll
    for (int uu = 0; uu < 4; ++uu) {
        int u = uu * 256 + t;
        int row = u >> 5, slot = u & 31;
        stoff[uu] = row * 256 + ((slot ^ (row & 7)) << 3);
    }
    const float4* gh = (const float4*)codh;   // 16B granules, [code][slot] linear
    const float4* gl = (const float4*)codl;

    // ---- stage chunk 0 into buf 0 ----
    float4 sth[4], stl[4];
    #pragma unroll
    for (int uu = 0; uu < 4; ++uu) {
        int u = uu * 256 + t;
        sth[uu] = gh[u];
        stl[uu] = gl[u];
    }
    #pragma unroll
    for (int uu = 0; uu < 4; ++uu) {
        *(float4*)(&Bh[0][stoff[uu]]) = sth[uu];
        *(float4*)(&Bl[0][stoff[uu]]) = stl[uu];
    }
    __syncthreads();

    float bv[16]; int bi[16];
    #pragma unroll
    for (int g = 0; g < 16; ++g) { bv[g] = 3.0e38f; bi[g] = 0; }

    const int cb = lr * 256;     // B-read base (shorts): code lr of the chunk
    const int cx = lr & 7;
    int c = 0;
    for (int ch = 0; ch < 32; ++ch) {
        // prefetch next chunk into registers
        if (ch < 31) {
            #pragma unroll
            for (int uu = 0; uu < 4; ++uu) {
                int u = (ch + 1) * 1024 + uu * 256 + t;
                sth[uu] = gh[u];
                stl[uu] = gl[u];
            }
        }
        // compute on buf[c]: one 32-row x 32-code tile, K=256
        f32x16 accP, accQ, accR;
        #pragma unroll
        for (int g = 0; g < 16; ++g) { accP[g] = 0.f; accQ[g] = 0.f; accR[g] = 0.f; }
        #pragma unroll
        for (int ks = 0; ks < 16; ++ks) {
            int slot = ks * 2 + lh;
            int off = cb + ((slot ^ cx) << 3);
            bf16x8 bh = *(const bf16x8*)(&Bh[c][off]);
            bf16x8 bl = *(const bf16x8*)(&Bl[c][off]);
            accP = MFMA32(ah[ks], bh, accP);
            accQ = MFMA32(ah[ks], bl, accQ);
            accR = MFMA32(al[ks], bh, accR);
        }
        int code = ch * 32 + lr;
        float cn = cnorm[code];
        #pragma unroll
        for (int g = 0; g < 16; ++g) {
            float d = cn - 2.f * (accP[g] + accQ[g] + accR[g]);
            if (d < bv[g]) { bv[g] = d; bi[g] = code; }
        }
        // write prefetched chunk into the other buffer
        if (ch < 31) {
            #pragma unroll
            for (int uu = 0; uu < 4; ++uu) {
                *(float4*)(&Bh[c ^ 1][stoff[uu]]) = sth[uu];
                *(float4*)(&Bl[c ^ 1][stoff[uu]]) = stl[uu];
            }
            __syncthreads();
        }
        c ^= 1;
    }

    // ---- reduce each reg-slot over its 32-lane code group (lexicographic) ----
    #pragma unroll
    for (int g = 0; g < 16; ++g) {
        float v = bv[g]; int i = bi[g];
        #pragma unroll
        for (int mask = 1; mask <= 16; mask <<= 1) {
            float ov = __shfl_xor(v, mask);
            int oi = __shfl_xor(i, mask);
            if (ov < v || (ov == v && oi < i)) { v = ov; i = oi; }
        }
        bv[g] = v; bi[g] = i;
    }
    // gather norms for the rows this lane's reg-slots map to (uniform-width shfl)
    float fnr[16];
    #pragma unroll
    for (int g = 0; g < 16; ++g) {
        int R = (g & 3) + 8 * (g >> 2) + 4 * lh;
        fnr[g] = __shfl(nrm, R);
    }

    float lp = 0.f;
    if (lr == 0) {   // lanes 0 and 32: winners for rows (g&3)+8*(g>>2)+4*lh
        #pragma unroll
        for (int g = 0; g < 16; ++g) {
            int R = (g & 3) + 8 * (g >> 2) + 4 * lh;
            enc[r0 + R] = bi[g];
            atomicAdd(&counts[bi[g]], 1);
            lp += fnr[g] + bv[g];
        }
    }
    lp += __shfl_xor(lp, 32);
    if (lane == 0) atomicAdd(lsum, lp);
}

// ============================ prep2: fc1 weight slices split ============================
// f1s[pos][out][c] = fc1w[out][c*16+pos]
__global__ __launch_bounds__(256) void prep2_kernel(
    const float* __restrict__ fc1w,
    unsigned short* __restrict__ f1h, unsigned short* __restrict__ f1l)
{
    int i = blockIdx.x * 256 + threadIdx.x;   // 2,097,152
    int pos = i >> 17, rem = i & 131071, o = rem >> 8, c = rem & 255;
    float v = fc1w[(size_t)o * 4096 + c * 16 + pos];
    unsigned short h, l; split2(v, &h, &l);
    f1h[i] = h; f1l[i] = l;
}

// ============================ lut: LUT[pos][code][out] = codes . W1-slice ============================
__global__ __launch_bounds__(256, 2) void lut_kernel(
    const unsigned short* __restrict__ codh, const unsigned short* __restrict__ codl,
    const unsigned short* __restrict__ f1h, const unsigned short* __restrict__ f1l,
    float* __restrict__ lut)
{
    const int t = threadIdx.x, b = blockIdx.x;
    const int pos = b >> 5, sub = b & 31, mblk = sub >> 2, nblk = sub & 3;
    const int wv = t >> 6, lane = t & 63, lq = lane >> 4, lm = lane & 15;
    const int mh = wv >> 1, nh = wv & 1;
    f32x4 acc[4][4];
    #pragma unroll
    for (int i = 0; i < 4; ++i)
        #pragma unroll
        for (int j = 0; j < 4; ++j) acc[i][j] = (f32x4){0.f, 0.f, 0.f, 0.f};
    #pragma unroll
    for (int ks = 0; ks < 8; ++ks) {
        bf16x8 ah[4], al[4];
        #pragma unroll
        for (int mt = 0; mt < 4; ++mt) {
            int code = mblk * 128 + mh * 64 + mt * 16 + lm;
            ah[mt] = *(const bf16x8*)(codh + (size_t)code * 256 + ks * 32 + lq * 8);
            al[mt] = *(const bf16x8*)(codl + (size_t)code * 256 + ks * 32 + lq * 8);
        }
        #pragma unroll
        for (int nt = 0; nt < 4; ++nt) {
            int o = nblk * 128 + nh * 64 + nt * 16 + lm;
            bf16x8 bh = *(const bf16x8*)(f1h + ((size_t)pos * 512 + o) * 256 + ks * 32 + lq * 8);
            bf16x8 bl = *(const bf16x8*)(f1l + ((size_t)pos * 512 + o) * 256 + ks * 32 + lq * 8);
            #pragma unroll
            for (int mt = 0; mt < 4; ++mt) {
                acc[mt][nt] = MFMA16(ah[mt], bh, acc[mt][nt]);
                acc[mt][nt] = MFMA16(ah[mt], bl, acc[mt][nt]);
                acc[mt][nt] = MFMA16(al[mt], bh, acc[mt][nt]);
            }
        }
    }
    #pragma unroll
    for (int nt = 0; nt < 4; ++nt) {
        int o = nblk * 128 + nh * 64 + nt * 16 + lm;
        #pragma unroll
        for (int mt = 0; mt < 4; ++mt)
            #pragma unroll
            for (int r = 0; r < 4; ++r) {
                int code = mblk * 128 + mh * 64 + mt * 16 + lq * 4 + r;
                lut[((size_t)pos * 1024 + code) * 512 + o] = acc[mt][nt][r];
            }
    }
}

// ============================ hsum: h = gelu(b1 + sum_pos LUT[pos][enc]) ============================
__device__ inline float gelu_tanh(float x) {
    float x3 = x * x * x;
    float u = 0.7978845608028654f * (x + 0.044715f * x3);
    return 0.5f * x * (1.0f + tanhf(u));
}

__global__ __launch_bounds__(256) void hsum_kernel(
    const int* __restrict__ enc, const float* __restrict__ lut,
    const float* __restrict__ fc1b, float* __restrict__ h)
{
    __shared__ int e[16];
    const int t = threadIdx.x, img = blockIdx.x;
    if (t < 16) e[t] = enc[img * 16 + t];
    __syncthreads();
    for (int rep = 0; rep < 2; ++rep) {
        int o = rep * 256 + t;
        float acc = fc1b[o];
        #pragma unroll
        for (int p = 0; p < 16; ++p)
            acc += lut[((size_t)p * 1024 + e[p]) * 512 + o];
        h[(size_t)img * 512 + o] = gelu_tanh(acc);
    }
}

// ============================ fc2 ============================
__global__ __launch_bounds__(256) void fc2_kernel(
    const float* __restrict__ h, const float* __restrict__ fc2w,
    const float* __restrict__ fc2b, float* __restrict__ out)
{
    __shared__ float ws2[10 * 512];
    const int t = threadIdx.x;
    for (int i = t; i < 5120; i += 256) ws2[i] = fc2w[i];
    __syncthreads();
    const int lane = t & 63, wv = t >> 6;
    const int n = blockIdx.x * 4 + wv;
    float acc[10];
    #pragma unroll
    for (int j = 0; j < 10; ++j) acc[j] = 0.f;
    #pragma unroll
    for (int i = 0; i < 8; ++i) {
        float hv = h[(size_t)n * 512 + lane + 64 * i];
        #pragma unroll
        for (int j = 0; j < 10; ++j) acc[j] += hv * ws2[j * 512 + lane + 64 * i];
    }
    #pragma unroll
    for (int j = 0; j < 10; ++j) {
        float v = acc[j];
        for (int off = 32; off; off >>= 1) v += __shfl_down(v, off);
        if (lane == 0) out[(size_t)n * 10 + j] = v + fc2b[j];
    }
}

// ============================ finalize ============================
__global__ __launch_bounds__(256) void finalize_kernel(
    const int* __restrict__ counts, const float* __restrict__ lsum,
    const int* __restrict__ idxp, float* __restrict__ out)
{
    __shared__ float red[256];
    const int t = threadIdx.x;
    const int Kc = (idxp[0] == 0) ? 512 : 1024;
    float s = 0.f;
    for (int k = t; k < Kc; k += 256) {
        float p = (float)counts[k] * (1.0f / 65536.0f);
        s += p * logf(p + 1e-10f);
    }
    red[t] = s;
    __syncthreads();
    for (int o = 128; o; o >>= 1) {
        if (t < o) red[t] += red[t + o];
        __syncthreads();
    }
    if (t == 0) {
        out[40960] = lsum[0] * (1.25f / 16777216.0f);   // (1+0.25) * mean over 65536*256
        out[40961] = expf(-red[0]);
    }
}

// ============================ launch ============================
extern "C" void kernel_launch(void* const* d_in, const int* in_sizes, int n_in,
                              void* d_out, int out_size, void* d_ws, size_t ws_size,
                              hipStream_t stream)
{
    const float* x     = (const float*)d_in[0];
    const float* w1    = (const float*)d_in[1];
    const float* b1    = (const float*)d_in[2];
    const float* w2    = (const float*)d_in[3];
    const float* b2    = (const float*)d_in[4];
    const float* w3    = (const float*)d_in[5];
    const float* b3    = (const float*)d_in[6];
    const float* code0 = (const float*)d_in[7];
    const float* code1 = (const float*)d_in[8];
    const float* fc1w  = (const float*)d_in[9];
    const float* fc1b  = (const float*)d_in[10];
    const float* fc2w  = (const float*)d_in[11];
    const float* fc2b  = (const float*)d_in[12];
    const int*   idxp  = (const int*)d_in[13];
    float* out = (float*)d_out;
    char* ws = (char*)d_ws;

    unsigned short* w1sh = (unsigned short*)(ws + OFF_W1SH);
    unsigned short* w1sl = (unsigned short*)(ws + OFF_W1SL);
    unsigned short* w2sh = (unsigned short*)(ws + OFF_W2SH);
    unsigned short* w2sl = (unsigned short*)(ws + OFF_W2SL);
    unsigned short* w3sh = (unsigned short*)(ws + OFF_W3SH);
    unsigned short* w3sl = (unsigned short*)(ws + OFF_W3SL);
    unsigned short* codh = (unsigned short*)(ws + OFF_CODH);
    unsigned short* codl = (unsigned short*)(ws + OFF_CODL);
    float* cnorm = (float*)(ws + OFF_CNORM);
    int*   counts= (int*)(ws + OFF_COUNTS);
    float* lsum  = (float*)(ws + OFF_LOSS);
    int*   enc   = (int*)(ws + OFF_ENC);
    unsigned short* y2h = (unsigned short*)(ws + OFF_BIG);
    unsigned short* y2l = (unsigned short*)(ws + OFF_BIG + 67108864);
    unsigned short* fh  = (unsigned short*)(ws + OFF_FLATS);
    unsigned short* fl  = (unsigned short*)(ws + OFF_FLATS + 33554432);
    // post-conv3 aliases (y2 region dead):
    float* lut = (float*)(ws + OFF_BIG);
    float* h   = (float*)(ws + OFF_BIG + 33554432);
    // post-vq aliases (flat region dead):
    unsigned short* f1h = (unsigned short*)(ws + OFF_FLATS);
    unsigned short* f1l = (unsigned short*)(ws + OFF_FLATS + 4194304);

    prep1_kernel<<<2481, 256, 0, stream>>>(w1, w2, w3, code0, code1, idxp,
                                           w1sh, w1sl, w2sh, w2sl, w3sh, w3sl,
                                           codh, codl, cnorm, counts, lsum);
    conv12_kernel<<<8192, 256, 0, stream>>>(x, w1sh, w1sl, b1, w2sh, w2sl, b2, y2h, y2l);
    conv3_kernel<<<512, 256, 0, stream>>>(y2h, y2l, w3sh, w3sl, b3, fh, fl);
    vq_kernel<<<512, 256, 0, stream>>>(fh, fl, codh, codl, cnorm, enc, counts, lsum);
    prep2_kernel<<<8192, 256, 0, stream>>>(fc1w, f1h, f1l);
    lut_kernel<<<512, 256, 0, stream>>>(codh, codl, f1h, f1l, lut);
    hsum_kernel<<<4096, 256, 0, stream>>>(enc, lut, fc1b, h);
    fc2_kernel<<<1024, 256, 0, stream>>>(h, fc2w, fc2b, out);
    finalize_kernel<<<1, 256, 0, stream>>>(counts, lsum, idxp, out);
}

// Round 11
// 1071.782 us; speedup vs baseline: 1.7181x; 1.5404x over previous
//
#include <hip/hip_runtime.h>
#include <math.h>

// ============================ MFMA types/helpers ============================
typedef short bf16x8 __attribute__((ext_vector_type(8)));   // 8 bf16 (4 VGPRs)
typedef float f32x4 __attribute__((ext_vector_type(4)));

#define MFMA16(a, b, c) __builtin_amdgcn_mfma_f32_16x16x32_bf16((a), (b), (c), 0, 0, 0)

__device__ inline unsigned short bf16_rn(float x) {
    unsigned u = __float_as_uint(x);
    unsigned r = u + 0x7FFFu + ((u >> 16) & 1u);
    return (unsigned short)(r >> 16);
}
__device__ inline float bf16_to_f(unsigned short h) {
    return __uint_as_float(((unsigned)h) << 16);
}
__device__ inline void split2(float x, unsigned short* hp, unsigned short* lp) {
    unsigned short h = bf16_rn(x);
    *hp = h;
    *lp = bf16_rn(x - bf16_to_f(h));
}

// ============================ workspace layout (bytes) ============================
static constexpr size_t OFF_W1SH  = 0;           // [64co][32k] shorts  (k 27..31 zero)
static constexpr size_t OFF_W1SL  = 4096;
static constexpr size_t OFF_W2SH  = 8192;        // [128co][576k] shorts, k = khw*64+ci
static constexpr size_t OFF_W2SL  = 155648;
static constexpr size_t OFF_W3SH  = 303104;      // [256co][1152k] shorts, k = khw*128+ci
static constexpr size_t OFF_W3SL  = 892928;
static constexpr size_t OFF_CODH  = 1482752;     // [1024][256] shorts (rows>=Kc zero)
static constexpr size_t OFF_CODL  = 2007040;
static constexpr size_t OFF_CNORM = 2531328;     // [1024] f32 (3e38 for >=Kc)
static constexpr size_t OFF_COUNTS= 2535424;     // [1024] int (legacy, unused)
static constexpr size_t OFF_LOSS  = 2539520;     // f32 (legacy, unused)
static constexpr size_t OFF_ENC   = 2539776;     // [65536] int
static constexpr size_t OFF_BIG   = 2801920;     // y2h(67108864)+y2l(67108864)
                                                 // post-conv3 reuse: LUT f32 (33554432) + h f32 (8388608)
                                                 // + hpart/lpart at +48MB (inside dead y2h)
static constexpr size_t OFF_HPART = OFF_BIG + 50331648;   // [64][1024] int (256KB)
static constexpr size_t OFF_LPART = OFF_HPART + 262144;   // [2048] f32 (8KB)
static constexpr size_t OFF_FLATS = 137019648;   // fh(33554432)+fl(33554432)
                                                 // post-vq reuse: fc1wsh(4194304)+fc1wsl(4194304)

// ============================ prep1: weight/code splits ============================
__global__ __launch_bounds__(256) void prep1_kernel(
    const float* __restrict__ w1, const float* __restrict__ w2,
    const float* __restrict__ w3, const float* __restrict__ code0,
    const float* __restrict__ code1, const int* __restrict__ idxp,
    unsigned short* __restrict__ w1sh, unsigned short* __restrict__ w1sl,
    unsigned short* __restrict__ w2sh, unsigned short* __restrict__ w2sl,
    unsigned short* __restrict__ w3sh, unsigned short* __restrict__ w3sl,
    unsigned short* __restrict__ codh, unsigned short* __restrict__ codl,
    float* __restrict__ cnorm)
{
    int i = blockIdx.x * 256 + threadIdx.x;
    const int Kc = (idxp[0] == 0) ? 512 : 1024;
    if (i < 2048) {                           // w1s [co][32], k=(kh*3+kw)*3+ci
        int co = i >> 5, k = i & 31;
        float v = 0.f;
        if (k < 27) {
            int khw = k / 3, ci = k - khw * 3;
            v = w1[(co * 3 + ci) * 9 + khw];
        }
        unsigned short h, l; split2(v, &h, &l);
        w1sh[i] = h; w1sl[i] = l; return;
    }
    i -= 2048;
    if (i < 73728) {                          // w2s [co][576], k=khw*64+ci
        int co = i / 576, k = i - co * 576;
        int khw = k >> 6, ci = k & 63;
        float v = w2[(co * 64 + ci) * 9 + khw];
        unsigned short h, l; split2(v, &h, &l);
        w2sh[i] = h; w2sl[i] = l; return;
    }
    i -= 73728;
    if (i < 294912) {                         // w3s [co][1152], k=khw*128+ci
        int co = i / 1152, k = i - co * 1152;
        int khw = k >> 7, ci = k & 127;
        float v = w3[(co * 128 + ci) * 9 + khw];
        unsigned short h, l; split2(v, &h, &l);
        w3sh[i] = h; w3sl[i] = l; return;
    }
    i -= 294912;
    if (i < 262144) {                         // codes [code][256]
        int code = i >> 8, c = i & 255;
        float v = 0.f;
        if (code < Kc) v = (code < 512) ? code0[code * 256 + c]
                                        : code1[(code - 512) * 256 + c];
        unsigned short h, l; split2(v, &h, &l);
        codh[i] = h; codl[i] = l; return;
    }
    i -= 262144;
    if (i < 1024) {                           // cnorm (exact fp32)
        float s;
        if (i < Kc) {
            const float* c = (i < 512) ? code0 + (size_t)i * 256
                                       : code1 + (size_t)(i - 512) * 256;
            s = 0.f;
            for (int k = 0; k < 256; ++k) s += c[k] * c[k];
        } else s = 3.0e38f;
        cnorm[i] = s; return;
    }
}

// ============================ conv12: fused conv1+conv2 (split-bf16 MFMA) ============================
__global__ __launch_bounds__(256, 2) void conv12_kernel(
    const float* __restrict__ x,
    const unsigned short* __restrict__ w1sh, const unsigned short* __restrict__ w1sl,
    const float* __restrict__ b1,
    const unsigned short* __restrict__ w2sh, const unsigned short* __restrict__ w2sl,
    const float* __restrict__ b2,
    unsigned short* __restrict__ y2h, unsigned short* __restrict__ y2l)
{
    __shared__ __align__(16) char smem[62496];
    float* xsp = (float*)smem;
    unsigned short* y1h = (unsigned short*)smem;
    unsigned short* y1l = (unsigned short*)(smem + 22032);
    unsigned short* Ah1 = (unsigned short*)(smem + 44064);
    unsigned short* Al1 = (unsigned short*)(smem + 53280);
    const int t = threadIdx.x;
    const int n = blockIdx.x >> 1, hh = blockIdx.x & 1;
    const int wv = t >> 6, lane = t & 63, lq = lane >> 4, lm = lane & 15;

    // ---- load x into padded LDS ----
    for (int i = t; i < 3468; i += 256) xsp[i] = 0.f;
    __syncthreads();
    const float* xn = x + (size_t)n * 3072;
    for (int i = t; i < 768; i += 256) {
        float4 v = ((const float4*)xn)[i];
        int ci = i >> 8, rem = i & 255, ih = rem >> 3, iw = (rem & 7) << 2;
        float* d = xsp + (size_t)(ci * 34 + ih + 1) * 34 + iw + 1;
        d[0] = v.x; d[1] = v.y; d[2] = v.z; d[3] = v.w;
    }
    __syncthreads();

    // ---- conv1 im2col ----
    for (int i = t; i < 4608; i += 256) {
        int px = i >> 5, k = i & 31;
        int l = px >> 4, ow = px & 15;
        float v = 0.f;
        if (k < 27 && !(hh == 0 && l == 0)) {
            int khw = k / 3, ci = k - khw * 3;
            int kh = khw / 3, kw = khw - kh * 3;
            int xr = 16 * hh - 2 + 2 * l + kh;      // padded row idx
            int xc = 2 * ow + kw;                   // padded col idx
            v = xsp[(size_t)(ci * 34 + xr) * 34 + xc];
        }
        unsigned short vh, vl; split2(v, &vh, &vl);
        int q = k >> 3, j = k & 7;
        Ah1[(q * 144 + px) * 8 + j] = vh;
        Al1[(q * 144 + px) * 8 + j] = vl;
    }
    __syncthreads();   // xsp dead; y1 region reusable

    // ---- zero y1 pads ----
    {
        unsigned* zh = (unsigned*)y1h; unsigned* zl = (unsigned*)y1l;
        for (int i = t; i < 612; i += 256) { zh[i] = 0u; zl[i] = 0u; }
        for (int i = t; i < 288; i += 256) {
            int l = 1 + i / 36, d = i - (l - 1) * 36;
            zh[l * 612 + d] = 0u; zl[l * 612 + d] = 0u;
        }
    }
    __syncthreads();

    // ---- conv1 via MFMA ----
    {
        f32x4 acc[9];
        #pragma unroll
        for (int mt = 0; mt < 9; ++mt) acc[mt] = (f32x4){0.f, 0.f, 0.f, 0.f};
        int co = wv * 16 + lm;
        bf16x8 bh = *(const bf16x8*)(w1sh + co * 32 + lq * 8);
        bf16x8 bl = *(const bf16x8*)(w1sl + co * 32 + lq * 8);
        #pragma unroll
        for (int mt = 0; mt < 9; ++mt) {
            bf16x8 ah = *(const bf16x8*)(Ah1 + (lq * 144 + mt * 16 + lm) * 8);
            bf16x8 al = *(const bf16x8*)(Al1 + (lq * 144 + mt * 16 + lm) * 8);
            acc[mt] = MFMA16(ah, bh, acc[mt]);
            acc[mt] = MFMA16(ah, bl, acc[mt]);
            acc[mt] = MFMA16(al, bh, acc[mt]);
        }
        float bias = b1[co];
        #pragma unroll
        for (int mt = 0; mt < 9; ++mt) {
            #pragma unroll
            for (int r = 0; r < 4; ++r) {
                int px = mt * 16 + lq * 4 + r;
                int l = px >> 4, ow = px & 15;
                if (hh == 0 && l == 0) continue;
                float v = fmaxf(acc[mt][r] + bias, 0.f);
                unsigned short vh, vl; split2(v, &vh, &vl);
                y1h[(l * 17 + ow + 1) * 72 + co] = vh;
                y1l[(l * 17 + ow + 1) * 72 + co] = vl;
            }
        }
    }
    __syncthreads();

    // ---- conv2 via MFMA ----
    {
        const int mt2 = wv >> 1, nh = wv & 1;
        f32x4 acc[4];
        #pragma unroll
        for (int i = 0; i < 4; ++i) acc[i] = (f32x4){0.f, 0.f, 0.f, 0.f};
        int px = mt2 * 16 + lm;
        int ohl = px >> 3, ow2 = px & 7;
        #pragma unroll
        for (int ks = 0; ks < 18; ++ks) {
            int khw = ks >> 1;
            int kh = khw / 3, kw = khw - kh * 3;
            int ci0 = (ks & 1) * 32 + lq * 8;
            int l = 2 * ohl + kh, c = 2 * ow2 + kw;
            bf16x8 ah = *(const bf16x8*)(y1h + (l * 17 + c) * 72 + ci0);
            bf16x8 al = *(const bf16x8*)(y1l + (l * 17 + c) * 72 + ci0);
            #pragma unroll
            for (int nt = 0; nt < 4; ++nt) {
                int co = nh * 64 + nt * 16 + lm;
                bf16x8 bh = *(const bf16x8*)(w2sh + co * 576 + ks * 32 + lq * 8);
                bf16x8 bl = *(const bf16x8*)(w2sl + co * 576 + ks * 32 + lq * 8);
                acc[nt] = MFMA16(ah, bh, acc[nt]);
                acc[nt] = MFMA16(ah, bl, acc[nt]);
                acc[nt] = MFMA16(al, bh, acc[nt]);
            }
        }
        #pragma unroll
        for (int nt = 0; nt < 4; ++nt) {
            int co = nh * 64 + nt * 16 + lm;
            float bias = b2[co];
            #pragma unroll
            for (int r = 0; r < 4; ++r) {
                int pxr = mt2 * 16 + lq * 4 + r;
                int ohr = pxr >> 3, owr = pxr & 7;
                float v = fmaxf(acc[nt][r] + bias, 0.f);
                unsigned short vh, vl; split2(v, &vh, &vl);
                size_t o = ((size_t)n * 64 + (hh * 4 + ohr) * 8 + owr) * 128 + co;
                y2h[o] = vh; y2l[o] = vl;
            }
        }
    }
}

// ============================ conv3: implicit GEMM 128px x 256co, K=1152 ============================
__global__ __launch_bounds__(256, 2) void conv3_kernel(
    const unsigned short* __restrict__ y2h, const unsigned short* __restrict__ y2l,
    const unsigned short* __restrict__ w3sh, const unsigned short* __restrict__ w3sl,
    const float* __restrict__ b3,
    unsigned short* __restrict__ fh, unsigned short* __restrict__ fl)
{
    __shared__ __align__(16) unsigned short Ah[4 * 128 * 8];   // [q][px][8]
    __shared__ __align__(16) unsigned short Al[4 * 128 * 8];
    const int t = threadIdx.x, b = blockIdx.x;
    const int wv = t >> 6, lane = t & 63, lq = lane >> 4, lm = lane & 15;
    const int mh = wv >> 1, nh = wv & 1;
    f32x4 acc[4][8];
    #pragma unroll
    for (int i = 0; i < 4; ++i)
        #pragma unroll
        for (int j = 0; j < 8; ++j) acc[i][j] = (f32x4){0.f, 0.f, 0.f, 0.f};
    const int gpx = t >> 1, gsel = t & 1;
    const int gimg = b * 8 + (gpx >> 4);
    const int gp = gpx & 15, goh = gp >> 2, gow = gp & 3;
    const unsigned short* gsrc = gsel ? y2l : y2h;
    unsigned short* gdst = gsel ? Al : Ah;

    for (int ks = 0; ks < 36; ++ks) {
        __syncthreads();
        {
            int khw = ks >> 2;
            int kh = khw / 3, kw = khw - kh * 3;
            int ci0 = (ks & 3) * 32;
            int ih = 2 * goh + kh - 1, iw = 2 * gow + kw - 1;
            if (ih >= 0 && ih < 8 && iw >= 0 && iw < 8) {
                const unsigned short* s = gsrc + ((size_t)gimg * 64 + ih * 8 + iw) * 128 + ci0;
                #pragma unroll
                for (int qq = 0; qq < 4; ++qq)
                    *(bf16x8*)(gdst + (qq * 128 + gpx) * 8) = *(const bf16x8*)(s + qq * 8);
            } else {
                #pragma unroll
                for (int qq = 0; qq < 4; ++qq)
                    *(bf16x8*)(gdst + (qq * 128 + gpx) * 8) = (bf16x8){0, 0, 0, 0, 0, 0, 0, 0};
            }
        }
        __syncthreads();
        bf16x8 ah[4], al[4];
        #pragma unroll
        for (int mt = 0; mt < 4; ++mt) {
            int mloc = mh * 64 + mt * 16 + lm;
            ah[mt] = *(const bf16x8*)(Ah + (lq * 128 + mloc) * 8);
            al[mt] = *(const bf16x8*)(Al + (lq * 128 + mloc) * 8);
        }
        #pragma unroll
        for (int nt = 0; nt < 8; ++nt) {
            int co = nh * 128 + nt * 16 + lm;
            bf16x8 bh = *(const bf16x8*)(w3sh + (size_t)co * 1152 + ks * 32 + lq * 8);
            bf16x8 bl = *(const bf16x8*)(w3sl + (size_t)co * 1152 + ks * 32 + lq * 8);
            #pragma unroll
            for (int mt = 0; mt < 4; ++mt) {
                acc[mt][nt] = MFMA16(ah[mt], bh, acc[mt][nt]);
                acc[mt][nt] = MFMA16(ah[mt], bl, acc[mt][nt]);
                acc[mt][nt] = MFMA16(al[mt], bh, acc[mt][nt]);
            }
        }
    }
    #pragma unroll
    for (int nt = 0; nt < 8; ++nt) {
        int co = nh * 128 + nt * 16 + lm;
        float bias = b3[co];
        #pragma unroll
        for (int mt = 0; mt < 4; ++mt) {
            #pragma unroll
            for (int r = 0; r < 4; ++r) {
                int mloc = mh * 64 + mt * 16 + lq * 4 + r;
                size_t row = (size_t)b * 128 + mloc;
                float v = fmaxf(acc[mt][nt][r] + bias, 0.f);
                unsigned short vh, vl; split2(v, &vh, &vl);
                fh[row * 256 + co] = vh;
                fl[row * 256 + co] = vl;
            }
        }
    }
}

// ============================ vq: fused distance GEMM + argmin + loss ============================
// ROUND 11: R1's fastest structure (642us) with ALL GLOBAL ATOMICS REMOVED.
// Theory: 7 structural variants (642-1144us) shared exactly one element --
// the epilogue's ~65536 atomicAdd(counts[bi]) (divergent, hot-code-
// concentrated) + ~2048 atomicAdd(lsum) (single address). On 8 non-coherent
// XCD L2s, same-line device-scope RMWs serialize via line ping-pong at
// ~hundreds of ns each -> ~400-700us of post-compute drain, invisible to
// SQ/TCC counters (waves done, pipes idle, dispatch not retired). Matches
// every observation: structure-invariance, idle pipes, vq-only slowness.
// Fix: epilogue writes enc + per-wave loss partials (plain stores); a new
// hist_kernel builds the histogram from enc via LDS atomics + partial
// stores; finalize sums partials (deterministic; atomic order was
// nondeterministic anyway). Compute path byte-identical to R1.
__global__ __launch_bounds__(256, 2) void vq_kernel(
    const unsigned short* __restrict__ fh, const unsigned short* __restrict__ fl,
    const unsigned short* __restrict__ codh, const unsigned short* __restrict__ codl,
    const float* __restrict__ cnorm, int* __restrict__ enc,
    float* __restrict__ lpart)
{
    __shared__ __align__(16) unsigned short Bh[2][8192];   // [buf][row(32)][swz slot(32)*8]
    __shared__ __align__(16) unsigned short Bl[2][8192];
    __shared__ float fnbuf[4 * 32];
    const int t = threadIdx.x;
    const int wv = t >> 6, lane = t & 63, lq = lane >> 4, lm = lane & 15;
    const int r0 = blockIdx.x * 128 + wv * 32;

    // ---- A fragments (full K=256) in registers ----
    bf16x8 ah[2][8], al[2][8];
    #pragma unroll
    for (int mt = 0; mt < 2; ++mt)
        #pragma unroll
        for (int ks = 0; ks < 8; ++ks) {
            size_t base = ((size_t)(r0 + mt * 16 + lm)) * 256 + ks * 32 + lq * 8;
            ah[mt][ks] = *(const bf16x8*)(fh + base);
            al[mt][ks] = *(const bf16x8*)(fl + base);
        }
    // ||f||^2 per row (reduce over the 4 k-quads)
    #pragma unroll
    for (int mt = 0; mt < 2; ++mt) {
        float s = 0.f;
        #pragma unroll
        for (int ks = 0; ks < 8; ++ks)
            #pragma unroll
            for (int j = 0; j < 8; ++j) {
                float v = bf16_to_f((unsigned short)ah[mt][ks][j]) +
                          bf16_to_f((unsigned short)al[mt][ks][j]);
                s += v * v;
            }
        s += __shfl_xor(s, 16);
        s += __shfl_xor(s, 32);
        if (lq == 0) fnbuf[wv * 32 + mt * 16 + lm] = s;
    }

    // ---- per-thread staging offsets (constant across chunks) ----
    int stoff[4];
    #pragma unroll
    for (int uu = 0; uu < 4; ++uu) {
        int u = uu * 256 + t;
        int row = u >> 5, slot = u & 31;
        stoff[uu] = row * 256 + ((slot ^ (row & 7)) << 3);
    }
    const float4* gh = (const float4*)codh;   // 16B granules, [code][slot] linear
    const float4* gl = (const float4*)codl;

    // ---- stage chunk 0 into buf 0 ----
    float4 sth[4], stl[4];
    #pragma unroll
    for (int uu = 0; uu < 4; ++uu) {
        int u = uu * 256 + t;
        sth[uu] = gh[u];
        stl[uu] = gl[u];
    }
    #pragma unroll
    for (int uu = 0; uu < 4; ++uu) {
        *(float4*)(&Bh[0][stoff[uu]]) = sth[uu];
        *(float4*)(&Bl[0][stoff[uu]]) = stl[uu];
    }
    __syncthreads();

    float bv[2][4]; int bi[2][4];
    #pragma unroll
    for (int mt = 0; mt < 2; ++mt)
        #pragma unroll
        for (int r = 0; r < 4; ++r) { bv[mt][r] = 3.0e38f; bi[mt][r] = 0; }

    int c = 0;
    for (int ch = 0; ch < 32; ++ch) {
        // prefetch next chunk into registers (hides L2 latency under MFMA phase)
        if (ch < 31) {
            #pragma unroll
            for (int uu = 0; uu < 4; ++uu) {
                int u = (ch + 1) * 1024 + uu * 256 + t;
                sth[uu] = gh[u];
                stl[uu] = gl[u];
            }
        }
        // compute on buf[c]
        f32x4 acc[2][2];
        #pragma unroll
        for (int i = 0; i < 2; ++i)
            #pragma unroll
            for (int j = 0; j < 2; ++j) acc[i][j] = (f32x4){0.f, 0.f, 0.f, 0.f};
        #pragma unroll
        for (int nt = 0; nt < 2; ++nt) {
            int code = nt * 16 + lm;              // row within chunk
            int cbase = code * 256;
            int cx = code & 7;
            #pragma unroll
            for (int ks = 0; ks < 8; ++ks) {
                int slot = ks * 4 + lq;
                int off = cbase + (((slot ^ cx)) << 3);
                bf16x8 bh = *(const bf16x8*)(&Bh[c][off]);
                bf16x8 bl = *(const bf16x8*)(&Bl[c][off]);
                acc[0][nt] = MFMA16(ah[0][ks], bh, acc[0][nt]);
                acc[0][nt] = MFMA16(ah[0][ks], bl, acc[0][nt]);
                acc[0][nt] = MFMA16(al[0][ks], bh, acc[0][nt]);
                acc[1][nt] = MFMA16(ah[1][ks], bh, acc[1][nt]);
                acc[1][nt] = MFMA16(ah[1][ks], bl, acc[1][nt]);
                acc[1][nt] = MFMA16(al[1][ks], bh, acc[1][nt]);
            }
        }
        #pragma unroll
        for (int nt = 0; nt < 2; ++nt) {
            int code = ch * 32 + nt * 16 + lm;
            float cn = cnorm[code];
            #pragma unroll
            for (int mt = 0; mt < 2; ++mt)
                #pragma unroll
                for (int r = 0; r < 4; ++r) {
                    float d = cn - 2.f * acc[mt][nt][r];
                    if (d < bv[mt][r]) { bv[mt][r] = d; bi[mt][r] = code; }
                }
        }
        // write prefetched chunk into the other buffer (safe: its last readers
        // were separated from us by the previous barrier)
        if (ch < 31) {
            #pragma unroll
            for (int uu = 0; uu < 4; ++uu) {
                *(float4*)(&Bh[c ^ 1][stoff[uu]]) = sth[uu];
                *(float4*)(&Bl[c ^ 1][stoff[uu]]) = stl[uu];
            }
            __syncthreads();
        }
        c ^= 1;
    }

    // reduce over the 16 column-lanes (lexicographic: value, then smaller index)
    #pragma unroll
    for (int mt = 0; mt < 2; ++mt)
        #pragma unroll
        for (int r = 0; r < 4; ++r) {
            float v = bv[mt][r]; int i = bi[mt][r];
            #pragma unroll
            for (int mask = 1; mask <= 8; mask <<= 1) {
                float ov = __shfl_xor(v, mask);
                int oi = __shfl_xor(i, mask);
                if (ov < v || (ov == v && oi < i)) { v = ov; i = oi; }
            }
            bv[mt][r] = v; bi[mt][r] = i;
        }
    // NO GLOBAL ATOMICS: write enc + per-wave loss partial only.
    float lp = 0.f;
    if (lm == 0) {
        #pragma unroll
        for (int mt = 0; mt < 2; ++mt)
            #pragma unroll
            for (int r = 0; r < 4; ++r) {
                int row_loc = mt * 16 + lq * 4 + r;
                enc[r0 + row_loc] = bi[mt][r];
                lp += fnbuf[wv * 32 + row_loc] + bv[mt][r];
            }
    }
    lp += __shfl_xor(lp, 16);
    lp += __shfl_xor(lp, 32);
    if (lane == 0) lpart[blockIdx.x * 4 + wv] = lp;
}

// ============================ hist: partial histograms of enc (LDS atomics only) ============================
__global__ __launch_bounds__(256) void hist_kernel(
    const int* __restrict__ enc, int* __restrict__ hpart)
{
    __shared__ int lh[1024];
    const int t = threadIdx.x, b = blockIdx.x;
    #pragma unroll
    for (int i = 0; i < 4; ++i) lh[t + i * 256] = 0;
    __syncthreads();
    #pragma unroll
    for (int i = 0; i < 4; ++i) {
        int e = enc[b * 1024 + t + i * 256];
        atomicAdd(&lh[e], 1);               // LDS atomic: per-CU, fast
    }
    __syncthreads();
    #pragma unroll
    for (int i = 0; i < 4; ++i)
        hpart[b * 1024 + t + i * 256] = lh[t + i * 256];
}

// ============================ prep2: fc1 weight slices split ============================
// f1s[pos][out][c] = fc1w[out][c*16+pos]
__global__ __launch_bounds__(256) void prep2_kernel(
    const float* __restrict__ fc1w,
    unsigned short* __restrict__ f1h, unsigned short* __restrict__ f1l)
{
    int i = blockIdx.x * 256 + threadIdx.x;   // 2,097,152
    int pos = i >> 17, rem = i & 131071, o = rem >> 8, c = rem & 255;
    float v = fc1w[(size_t)o * 4096 + c * 16 + pos];
    unsigned short h, l; split2(v, &h, &l);
    f1h[i] = h; f1l[i] = l;
}

// ============================ lut: LUT[pos][code][out] = codes . W1-slice ============================
__global__ __launch_bounds__(256, 2) void lut_kernel(
    const unsigned short* __restrict__ codh, const unsigned short* __restrict__ codl,
    const unsigned short* __restrict__ f1h, const unsigned short* __restrict__ f1l,
    float* __restrict__ lut)
{
    const int t = threadIdx.x, b = blockIdx.x;
    const int pos = b >> 5, sub = b & 31, mblk = sub >> 2, nblk = sub & 3;
    const int wv = t >> 6, lane = t & 63, lq = lane >> 4, lm = lane & 15;
    const int mh = wv >> 1, nh = wv & 1;
    f32x4 acc[4][4];
    #pragma unroll
    for (int i = 0; i < 4; ++i)
        #pragma unroll
        for (int j = 0; j < 4; ++j) acc[i][j] = (f32x4){0.f, 0.f, 0.f, 0.f};
    #pragma unroll
    for (int ks = 0; ks < 8; ++ks) {
        bf16x8 ah[4], al[4];
        #pragma unroll
        for (int mt = 0; mt < 4; ++mt) {
            int code = mblk * 128 + mh * 64 + mt * 16 + lm;
            ah[mt] = *(const bf16x8*)(codh + (size_t)code * 256 + ks * 32 + lq * 8);
            al[mt] = *(const bf16x8*)(codl + (size_t)code * 256 + ks * 32 + lq * 8);
        }
        #pragma unroll
        for (int nt = 0; nt < 4; ++nt) {
            int o = nblk * 128 + nh * 64 + nt * 16 + lm;
            bf16x8 bh = *(const bf16x8*)(f1h + ((size_t)pos * 512 + o) * 256 + ks * 32 + lq * 8);
            bf16x8 bl = *(const bf16x8*)(f1l + ((size_t)pos * 512 + o) * 256 + ks * 32 + lq * 8);
            #pragma unroll
            for (int mt = 0; mt < 4; ++mt) {
                acc[mt][nt] = MFMA16(ah[mt], bh, acc[mt][nt]);
                acc[mt][nt] = MFMA16(ah[mt], bl, acc[mt][nt]);
                acc[mt][nt] = MFMA16(al[mt], bh, acc[mt][nt]);
            }
        }
    }
    #pragma unroll
    for (int nt = 0; nt < 4; ++nt) {
        int o = nblk * 128 + nh * 64 + nt * 16 + lm;
        #pragma unroll
        for (int mt = 0; mt < 4; ++mt)
            #pragma unroll
            for (int r = 0; r < 4; ++r) {
                int code = mblk * 128 + mh * 64 + mt * 16 + lq * 4 + r;
                lut[((size_t)pos * 1024 + code) * 512 + o] = acc[mt][nt][r];
            }
    }
}

// ============================ hsum: h = gelu(b1 + sum_pos LUT[pos][enc]) ============================
__device__ inline float gelu_tanh(float x) {
    float x3 = x * x * x;
    float u = 0.7978845608028654f * (x + 0.044715f * x3);
    return 0.5f * x * (1.0f + tanhf(u));
}

__global__ __launch_bounds__(256) void hsum_kernel(
    const int* __restrict__ enc, const float* __restrict__ lut,
    const float* __restrict__ fc1b, float* __restrict__ h)
{
    __shared__ int e[16];
    const int t = threadIdx.x, img = blockIdx.x;
    if (t < 16) e[t] = enc[img * 16 + t];
    __syncthreads();
    for (int rep = 0; rep < 2; ++rep) {
        int o = rep * 256 + t;
        float acc = fc1b[o];
        #pragma unroll
        for (int p = 0; p < 16; ++p)
            acc += lut[((size_t)p * 1024 + e[p]) * 512 + o];
        h[(size_t)img * 512 + o] = gelu_tanh(acc);
    }
}

// ============================ fc2 ============================
__global__ __launch_bounds__(256) void fc2_kernel(
    const float* __restrict__ h, const float* __restrict__ fc2w,
    const float* __restrict__ fc2b, float* __restrict__ out)
{
    __shared__ float ws2[10 * 512];
    const int t = threadIdx.x;
    for (int i = t; i < 5120; i += 256) ws2[i] = fc2w[i];
    __syncthreads();
    const int lane = t & 63, wv = t >> 6;
    const int n = blockIdx.x * 4 + wv;
    float acc[10];
    #pragma unroll
    for (int j = 0; j < 10; ++j) acc[j] = 0.f;
    #pragma unroll
    for (int i = 0; i < 8; ++i) {
        float hv = h[(size_t)n * 512 + lane + 64 * i];
        #pragma unroll
        for (int j = 0; j < 10; ++j) acc[j] += hv * ws2[j * 512 + lane + 64 * i];
    }
    #pragma unroll
    for (int j = 0; j < 10; ++j) {
        float v = acc[j];
        for (int off = 32; off; off >>= 1) v += __shfl_down(v, off);
        if (lane == 0) out[(size_t)n * 10 + j] = v + fc2b[j];
    }
}

// ============================ finalize ============================
__global__ __launch_bounds__(256) void finalize_kernel(
    const int* __restrict__ hpart, const float* __restrict__ lpart,
    const int* __restrict__ idxp, float* __restrict__ out)
{
    __shared__ float red[256], red2[256];
    const int t = threadIdx.x;
    const int Kc = (idxp[0] == 0) ? 512 : 1024;
    float s = 0.f;
    for (int k = t; k < Kc; k += 256) {
        int c = 0;
        for (int p = 0; p < 64; ++p) c += hpart[p * 1024 + k];
        float pr = (float)c * (1.0f / 65536.0f);
        s += pr * logf(pr + 1e-10f);
    }
    float ls = 0.f;
    for (int j = t; j < 2048; j += 256) ls += lpart[j];
    red[t] = s; red2[t] = ls;
    __syncthreads();
    for (int o = 128; o; o >>= 1) {
        if (t < o) { red[t] += red[t + o]; red2[t] += red2[t + o]; }
        __syncthreads();
    }
    if (t == 0) {
        out[40960] = red2[0] * (1.25f / 16777216.0f);   // (1+0.25) * mean over 65536*256
        out[40961] = expf(-red[0]);
    }
}

// ============================ launch ============================
extern "C" void kernel_launch(void* const* d_in, const int* in_sizes, int n_in,
                              void* d_out, int out_size, void* d_ws, size_t ws_size,
                              hipStream_t stream)
{
    const float* x     = (const float*)d_in[0];
    const float* w1    = (const float*)d_in[1];
    const float* b1    = (const float*)d_in[2];
    const float* w2    = (const float*)d_in[3];
    const float* b2    = (const float*)d_in[4];
    const float* w3    = (const float*)d_in[5];
    const float* b3    = (const float*)d_in[6];
    const float* code0 = (const float*)d_in[7];
    const float* code1 = (const float*)d_in[8];
    const float* fc1w  = (const float*)d_in[9];
    const float* fc1b  = (const float*)d_in[10];
    const float* fc2w  = (const float*)d_in[11];
    const float* fc2b  = (const float*)d_in[12];
    const int*   idxp  = (const int*)d_in[13];
    float* out = (float*)d_out;
    char* ws = (char*)d_ws;

    unsigned short* w1sh = (unsigned short*)(ws + OFF_W1SH);
    unsigned short* w1sl = (unsigned short*)(ws + OFF_W1SL);
    unsigned short* w2sh = (unsigned short*)(ws + OFF_W2SH);
    unsigned short* w2sl = (unsigned short*)(ws + OFF_W2SL);
    unsigned short* w3sh = (unsigned short*)(ws + OFF_W3SH);
    unsigned short* w3sl = (unsigned short*)(ws + OFF_W3SL);
    unsigned short* codh = (unsigned short*)(ws + OFF_CODH);
    unsigned short* codl = (unsigned short*)(ws + OFF_CODL);
    float* cnorm = (float*)(ws + OFF_CNORM);
    int*   enc   = (int*)(ws + OFF_ENC);
    unsigned short* y2h = (unsigned short*)(ws + OFF_BIG);
    unsigned short* y2l = (unsigned short*)(ws + OFF_BIG + 67108864);
    unsigned short* fh  = (unsigned short*)(ws + OFF_FLATS);
    unsigned short* fl  = (unsigned short*)(ws + OFF_FLATS + 33554432);
    // post-conv3 aliases (y2 region dead):
    float* lut = (float*)(ws + OFF_BIG);
    float* h   = (float*)(ws + OFF_BIG + 33554432);
    int*   hpart = (int*)(ws + OFF_HPART);
    float* lpart = (float*)(ws + OFF_LPART);
    // post-vq aliases (flat region dead):
    unsigned short* f1h = (unsigned short*)(ws + OFF_FLATS);
    unsigned short* f1l = (unsigned short*)(ws + OFF_FLATS + 4194304);

    prep1_kernel<<<2481, 256, 0, stream>>>(w1, w2, w3, code0, code1, idxp,
                                           w1sh, w1sl, w2sh, w2sl, w3sh, w3sl,
                                           codh, codl, cnorm);
    conv12_kernel<<<8192, 256, 0, stream>>>(x, w1sh, w1sl, b1, w2sh, w2sl, b2, y2h, y2l);
    conv3_kernel<<<512, 256, 0, stream>>>(y2h, y2l, w3sh, w3sl, b3, fh, fl);
    vq_kernel<<<512, 256, 0, stream>>>(fh, fl, codh, codl, cnorm, enc, lpart);
    hist_kernel<<<64, 256, 0, stream>>>(enc, hpart);
    prep2_kernel<<<8192, 256, 0, stream>>>(fc1w, f1h, f1l);
    lut_kernel<<<512, 256, 0, stream>>>(codh, codl, f1h, f1l, lut);
    hsum_kernel<<<4096, 256, 0, stream>>>(enc, lut, fc1b, h);
    fc2_kernel<<<1024, 256, 0, stream>>>(h, fc2w, fc2b, out);
    finalize_kernel<<<1, 256, 0, stream>>>(hpart, lpart, idxp, out);
}

// Round 12
// 781.548 us; speedup vs baseline: 2.3561x; 1.3714x over previous
//
#include <hip/hip_runtime.h>
#include <math.h>

// ============================ MFMA types/helpers ============================
typedef short bf16x8 __attribute__((ext_vector_type(8)));   // 8 bf16 (4 VGPRs)
typedef float f32x4 __attribute__((ext_vector_type(4)));

#define MFMA16(a, b, c) __builtin_amdgcn_mfma_f32_16x16x32_bf16((a), (b), (c), 0, 0, 0)

__device__ inline unsigned short bf16_rn(float x) {
    unsigned u = __float_as_uint(x);
    unsigned r = u + 0x7FFFu + ((u >> 16) & 1u);
    return (unsigned short)(r >> 16);
}
__device__ inline float bf16_to_f(unsigned short h) {
    return __uint_as_float(((unsigned)h) << 16);
}
__device__ inline void split2(float x, unsigned short* hp, unsigned short* lp) {
    unsigned short h = bf16_rn(x);
    *hp = h;
    *lp = bf16_rn(x - bf16_to_f(h));
}

// ============================ workspace layout (bytes) ============================
// ROUND 12: weight layouts transposed to K-inner-32 ([kblock][n][32]) so every
// B-fragment load instruction covers contiguous 1KB (was: 16 lanes x 1152B
// stride = ~64 L1 lines per instruction -- the conv12/conv3/lut wall).
static constexpr size_t OFF_W1SH  = 0;           // [64co][32k] shorts (already K-inner)
static constexpr size_t OFF_W1SL  = 4096;
static constexpr size_t OFF_W2SH  = 8192;        // [18kb][128co][32] shorts
static constexpr size_t OFF_W2SL  = 155648;
static constexpr size_t OFF_W3SH  = 303104;      // [36kb][256co][32] shorts
static constexpr size_t OFF_W3SL  = 892928;
static constexpr size_t OFF_CODH  = 1482752;     // [1024][256] shorts (rows>=Kc zero) - vq layout
static constexpr size_t OFF_CODL  = 2007040;
static constexpr size_t OFF_CNORM = 2531328;     // [1024] f32 (3e38 for >=Kc)
static constexpr size_t OFF_COUNTS= 2535424;     // legacy
static constexpr size_t OFF_LOSS  = 2539520;     // legacy
static constexpr size_t OFF_ENC   = 2539776;     // [65536] int
static constexpr size_t OFF_BIG   = 2801920;     // y2h(67108864)+y2l(67108864)
                                                 // post-conv3 reuse: LUT f32 (33554432) + h f32 (8388608)
static constexpr size_t OFF_HPART = OFF_BIG + 50331648;   // [64][1024] int (256KB)
static constexpr size_t OFF_LPART = OFF_HPART + 262144;   // [2048] f32 (8KB)
static constexpr size_t OFF_FLATS = 137019648;   // fh(33554432)+fl(33554432)
                                                 // post-vq reuse: f1h(8388608)+f1l(8388608) [kb layout]
static constexpr size_t OFF_CODTH = 204128512;   // [8kb][1024code][32] shorts (524288 B)
static constexpr size_t OFF_CODTL = 204652800;   // total 205,177,088 < 212,515,840 proven

// ============================ prep1: weight/code splits ============================
__global__ __launch_bounds__(256) void prep1_kernel(
    const float* __restrict__ w1, const float* __restrict__ w2,
    const float* __restrict__ w3, const float* __restrict__ code0,
    const float* __restrict__ code1, const int* __restrict__ idxp,
    unsigned short* __restrict__ w1sh, unsigned short* __restrict__ w1sl,
    unsigned short* __restrict__ w2sh, unsigned short* __restrict__ w2sl,
    unsigned short* __restrict__ w3sh, unsigned short* __restrict__ w3sl,
    unsigned short* __restrict__ codh, unsigned short* __restrict__ codl,
    unsigned short* __restrict__ codTh, unsigned short* __restrict__ codTl,
    float* __restrict__ cnorm)
{
    int i = blockIdx.x * 256 + threadIdx.x;
    const int Kc = (idxp[0] == 0) ? 512 : 1024;
    if (i < 2048) {                           // w1s [co][32], k=(kh*3+kw)*3+ci
        int co = i >> 5, k = i & 31;
        float v = 0.f;
        if (k < 27) {
            int khw = k / 3, ci = k - khw * 3;
            v = w1[(co * 3 + ci) * 9 + khw];
        }
        unsigned short h, l; split2(v, &h, &l);
        w1sh[i] = h; w1sl[i] = l; return;
    }
    i -= 2048;
    if (i < 73728) {                          // w2s: k=khw*64+ci -> [k>>5][co][k&31]
        int co = i / 576, k = i - co * 576;
        int khw = k >> 6, ci = k & 63;
        float v = w2[(co * 64 + ci) * 9 + khw];
        unsigned short h, l; split2(v, &h, &l);
        int d = ((k >> 5) * 128 + co) * 32 + (k & 31);
        w2sh[d] = h; w2sl[d] = l; return;
    }
    i -= 73728;
    if (i < 294912) {                         // w3s: k=khw*128+ci -> [k>>5][co][k&31]
        int co = i / 1152, k = i - co * 1152;
        int khw = k >> 7, ci = k & 127;
        float v = w3[(co * 128 + ci) * 9 + khw];
        unsigned short h, l; split2(v, &h, &l);
        int d = ((k >> 5) * 256 + co) * 32 + (k & 31);
        w3sh[d] = h; w3sl[d] = l; return;
    }
    i -= 294912;
    if (i < 262144) {                         // codes [code][256] + transposed [c>>5][code][c&31]
        int code = i >> 8, c = i & 255;
        float v = 0.f;
        if (code < Kc) v = (code < 512) ? code0[code * 256 + c]
                                        : code1[(code - 512) * 256 + c];
        unsigned short h, l; split2(v, &h, &l);
        codh[i] = h; codl[i] = l;
        int d = ((c >> 5) * 1024 + code) * 32 + (c & 31);
        codTh[d] = h; codTl[d] = l; return;
    }
    i -= 262144;
    if (i < 1024) {                           // cnorm (exact fp32)
        float s;
        if (i < Kc) {
            const float* c = (i < 512) ? code0 + (size_t)i * 256
                                       : code1 + (size_t)(i - 512) * 256;
            s = 0.f;
            for (int k = 0; k < 256; ++k) s += c[k] * c[k];
        } else s = 3.0e38f;
        cnorm[i] = s; return;
    }
}

// ============================ conv12: fused conv1+conv2 (split-bf16 MFMA) ============================
__global__ __launch_bounds__(256, 2) void conv12_kernel(
    const float* __restrict__ x,
    const unsigned short* __restrict__ w1sh, const unsigned short* __restrict__ w1sl,
    const float* __restrict__ b1,
    const unsigned short* __restrict__ w2sh, const unsigned short* __restrict__ w2sl,
    const float* __restrict__ b2,
    unsigned short* __restrict__ y2h, unsigned short* __restrict__ y2l)
{
    __shared__ __align__(16) char smem[62496];
    float* xsp = (float*)smem;
    unsigned short* y1h = (unsigned short*)smem;
    unsigned short* y1l = (unsigned short*)(smem + 22032);
    unsigned short* Ah1 = (unsigned short*)(smem + 44064);
    unsigned short* Al1 = (unsigned short*)(smem + 53280);
    const int t = threadIdx.x;
    const int n = blockIdx.x >> 1, hh = blockIdx.x & 1;
    const int wv = t >> 6, lane = t & 63, lq = lane >> 4, lm = lane & 15;

    // ---- load x into padded LDS ----
    for (int i = t; i < 3468; i += 256) xsp[i] = 0.f;
    __syncthreads();
    const float* xn = x + (size_t)n * 3072;
    for (int i = t; i < 768; i += 256) {
        float4 v = ((const float4*)xn)[i];
        int ci = i >> 8, rem = i & 255, ih = rem >> 3, iw = (rem & 7) << 2;
        float* d = xsp + (size_t)(ci * 34 + ih + 1) * 34 + iw + 1;
        d[0] = v.x; d[1] = v.y; d[2] = v.z; d[3] = v.w;
    }
    __syncthreads();

    // ---- conv1 im2col ----
    for (int i = t; i < 4608; i += 256) {
        int px = i >> 5, k = i & 31;
        int l = px >> 4, ow = px & 15;
        float v = 0.f;
        if (k < 27 && !(hh == 0 && l == 0)) {
            int khw = k / 3, ci = k - khw * 3;
            int kh = khw / 3, kw = khw - kh * 3;
            int xr = 16 * hh - 2 + 2 * l + kh;      // padded row idx
            int xc = 2 * ow + kw;                   // padded col idx
            v = xsp[(size_t)(ci * 34 + xr) * 34 + xc];
        }
        unsigned short vh, vl; split2(v, &vh, &vl);
        int q = k >> 3, j = k & 7;
        Ah1[(q * 144 + px) * 8 + j] = vh;
        Al1[(q * 144 + px) * 8 + j] = vl;
    }
    __syncthreads();   // xsp dead; y1 region reusable

    // ---- zero y1 pads ----
    {
        unsigned* zh = (unsigned*)y1h; unsigned* zl = (unsigned*)y1l;
        for (int i = t; i < 612; i += 256) { zh[i] = 0u; zl[i] = 0u; }
        for (int i = t; i < 288; i += 256) {
            int l = 1 + i / 36, d = i - (l - 1) * 36;
            zh[l * 612 + d] = 0u; zl[l * 612 + d] = 0u;
        }
    }
    __syncthreads();

    // ---- conv1 via MFMA ----
    {
        f32x4 acc[9];
        #pragma unroll
        for (int mt = 0; mt < 9; ++mt) acc[mt] = (f32x4){0.f, 0.f, 0.f, 0.f};
        int co = wv * 16 + lm;
        bf16x8 bh = *(const bf16x8*)(w1sh + co * 32 + lq * 8);
        bf16x8 bl = *(const bf16x8*)(w1sl + co * 32 + lq * 8);
        #pragma unroll
        for (int mt = 0; mt < 9; ++mt) {
            bf16x8 ah = *(const bf16x8*)(Ah1 + (lq * 144 + mt * 16 + lm) * 8);
            bf16x8 al = *(const bf16x8*)(Al1 + (lq * 144 + mt * 16 + lm) * 8);
            acc[mt] = MFMA16(ah, bh, acc[mt]);
            acc[mt] = MFMA16(ah, bl, acc[mt]);
            acc[mt] = MFMA16(al, bh, acc[mt]);
        }
        float bias = b1[co];
        #pragma unroll
        for (int mt = 0; mt < 9; ++mt) {
            #pragma unroll
            for (int r = 0; r < 4; ++r) {
                int px = mt * 16 + lq * 4 + r;
                int l = px >> 4, ow = px & 15;
                if (hh == 0 && l == 0) continue;
                float v = fmaxf(acc[mt][r] + bias, 0.f);
                unsigned short vh, vl; split2(v, &vh, &vl);
                y1h[(l * 17 + ow + 1) * 72 + co] = vh;
                y1l[(l * 17 + ow + 1) * 72 + co] = vl;
            }
        }
    }
    __syncthreads();

    // ---- conv2 via MFMA (B loads now K-inner-32: contiguous 1KB per instr) ----
    {
        const int mt2 = wv >> 1, nh = wv & 1;
        f32x4 acc[4];
        #pragma unroll
        for (int i = 0; i < 4; ++i) acc[i] = (f32x4){0.f, 0.f, 0.f, 0.f};
        int px = mt2 * 16 + lm;
        int ohl = px >> 3, ow2 = px & 7;
        #pragma unroll
        for (int ks = 0; ks < 18; ++ks) {
            int khw = ks >> 1;
            int kh = khw / 3, kw = khw - kh * 3;
            int ci0 = (ks & 1) * 32 + lq * 8;
            int l = 2 * ohl + kh, c = 2 * ow2 + kw;
            bf16x8 ah = *(const bf16x8*)(y1h + (l * 17 + c) * 72 + ci0);
            bf16x8 al = *(const bf16x8*)(y1l + (l * 17 + c) * 72 + ci0);
            #pragma unroll
            for (int nt = 0; nt < 4; ++nt) {
                int co = nh * 64 + nt * 16 + lm;
                bf16x8 bh = *(const bf16x8*)(w2sh + (ks * 128 + co) * 32 + lq * 8);
                bf16x8 bl = *(const bf16x8*)(w2sl + (ks * 128 + co) * 32 + lq * 8);
                acc[nt] = MFMA16(ah, bh, acc[nt]);
                acc[nt] = MFMA16(ah, bl, acc[nt]);
                acc[nt] = MFMA16(al, bh, acc[nt]);
            }
        }
        #pragma unroll
        for (int nt = 0; nt < 4; ++nt) {
            int co = nh * 64 + nt * 16 + lm;
            float bias = b2[co];
            #pragma unroll
            for (int r = 0; r < 4; ++r) {
                int pxr = mt2 * 16 + lq * 4 + r;
                int ohr = pxr >> 3, owr = pxr & 7;
                float v = fmaxf(acc[nt][r] + bias, 0.f);
                unsigned short vh, vl; split2(v, &vh, &vl);
                size_t o = ((size_t)n * 64 + (hh * 4 + ohr) * 8 + owr) * 128 + co;
                y2h[o] = vh; y2l[o] = vl;
            }
        }
    }
}

// ============================ conv3: implicit GEMM 128px x 256co, K=1152 ============================
__global__ __launch_bounds__(256, 2) void conv3_kernel(
    const unsigned short* __restrict__ y2h, const unsigned short* __restrict__ y2l,
    const unsigned short* __restrict__ w3sh, const unsigned short* __restrict__ w3sl,
    const float* __restrict__ b3,
    unsigned short* __restrict__ fh, unsigned short* __restrict__ fl)
{
    __shared__ __align__(16) unsigned short Ah[4 * 128 * 8];   // [q][px][8]
    __shared__ __align__(16) unsigned short Al[4 * 128 * 8];
    const int t = threadIdx.x, b = blockIdx.x;
    const int wv = t >> 6, lane = t & 63, lq = lane >> 4, lm = lane & 15;
    const int mh = wv >> 1, nh = wv & 1;
    f32x4 acc[4][8];
    #pragma unroll
    for (int i = 0; i < 4; ++i)
        #pragma unroll
        for (int j = 0; j < 8; ++j) acc[i][j] = (f32x4){0.f, 0.f, 0.f, 0.f};
    const int gpx = t >> 1, gsel = t & 1;
    const int gimg = b * 8 + (gpx >> 4);
    const int gp = gpx & 15, goh = gp >> 2, gow = gp & 3;
    const unsigned short* gsrc = gsel ? y2l : y2h;
    unsigned short* gdst = gsel ? Al : Ah;

    for (int ks = 0; ks < 36; ++ks) {
        __syncthreads();
        {
            int khw = ks >> 2;
            int kh = khw / 3, kw = khw - kh * 3;
            int ci0 = (ks & 3) * 32;
            int ih = 2 * goh + kh - 1, iw = 2 * gow + kw - 1;
            if (ih >= 0 && ih < 8 && iw >= 0 && iw < 8) {
                const unsigned short* s = gsrc + ((size_t)gimg * 64 + ih * 8 + iw) * 128 + ci0;
                #pragma unroll
                for (int qq = 0; qq < 4; ++qq)
                    *(bf16x8*)(gdst + (qq * 128 + gpx) * 8) = *(const bf16x8*)(s + qq * 8);
            } else {
                #pragma unroll
                for (int qq = 0; qq < 4; ++qq)
                    *(bf16x8*)(gdst + (qq * 128 + gpx) * 8) = (bf16x8){0, 0, 0, 0, 0, 0, 0, 0};
            }
        }
        __syncthreads();
        bf16x8 ah[4], al[4];
        #pragma unroll
        for (int mt = 0; mt < 4; ++mt) {
            int mloc = mh * 64 + mt * 16 + lm;
            ah[mt] = *(const bf16x8*)(Ah + (lq * 128 + mloc) * 8);
            al[mt] = *(const bf16x8*)(Al + (lq * 128 + mloc) * 8);
        }
        #pragma unroll
        for (int nt = 0; nt < 8; ++nt) {
            int co = nh * 128 + nt * 16 + lm;
            bf16x8 bh = *(const bf16x8*)(w3sh + (size_t)(ks * 256 + co) * 32 + lq * 8);
            bf16x8 bl = *(const bf16x8*)(w3sl + (size_t)(ks * 256 + co) * 32 + lq * 8);
            #pragma unroll
            for (int mt = 0; mt < 4; ++mt) {
                acc[mt][nt] = MFMA16(ah[mt], bh, acc[mt][nt]);
                acc[mt][nt] = MFMA16(ah[mt], bl, acc[mt][nt]);
                acc[mt][nt] = MFMA16(al[mt], bh, acc[mt][nt]);
            }
        }
    }
    #pragma unroll
    for (int nt = 0; nt < 8; ++nt) {
        int co = nh * 128 + nt * 16 + lm;
        float bias = b3[co];
        #pragma unroll
        for (int mt = 0; mt < 4; ++mt) {
            #pragma unroll
            for (int r = 0; r < 4; ++r) {
                int mloc = mh * 64 + mt * 16 + lq * 4 + r;
                size_t row = (size_t)b * 128 + mloc;
                float v = fmaxf(acc[mt][nt][r] + bias, 0.f);
                unsigned short vh, vl; split2(v, &vh, &vl);
                fh[row * 256 + co] = vh;
                fl[row * 256 + co] = vl;
            }
        }
    }
}

// ============================ vq: fused distance GEMM + argmin + loss ============================
// (R11's atomic-free version -- confirmed ~85us. Unchanged.)
__global__ __launch_bounds__(256, 2) void vq_kernel(
    const unsigned short* __restrict__ fh, const unsigned short* __restrict__ fl,
    const unsigned short* __restrict__ codh, const unsigned short* __restrict__ codl,
    const float* __restrict__ cnorm, int* __restrict__ enc,
    float* __restrict__ lpart)
{
    __shared__ __align__(16) unsigned short Bh[2][8192];   // [buf][row(32)][swz slot(32)*8]
    __shared__ __align__(16) unsigned short Bl[2][8192];
    __shared__ float fnbuf[4 * 32];
    const int t = threadIdx.x;
    const int wv = t >> 6, lane = t & 63, lq = lane >> 4, lm = lane & 15;
    const int r0 = blockIdx.x * 128 + wv * 32;

    // ---- A fragments (full K=256) in registers ----
    bf16x8 ah[2][8], al[2][8];
    #pragma unroll
    for (int mt = 0; mt < 2; ++mt)
        #pragma unroll
        for (int ks = 0; ks < 8; ++ks) {
            size_t base = ((size_t)(r0 + mt * 16 + lm)) * 256 + ks * 32 + lq * 8;
            ah[mt][ks] = *(const bf16x8*)(fh + base);
            al[mt][ks] = *(const bf16x8*)(fl + base);
        }
    // ||f||^2 per row (reduce over the 4 k-quads)
    #pragma unroll
    for (int mt = 0; mt < 2; ++mt) {
        float s = 0.f;
        #pragma unroll
        for (int ks = 0; ks < 8; ++ks)
            #pragma unroll
            for (int j = 0; j < 8; ++j) {
                float v = bf16_to_f((unsigned short)ah[mt][ks][j]) +
                          bf16_to_f((unsigned short)al[mt][ks][j]);
                s += v * v;
            }
        s += __shfl_xor(s, 16);
        s += __shfl_xor(s, 32);
        if (lq == 0) fnbuf[wv * 32 + mt * 16 + lm] = s;
    }

    // ---- per-thread staging offsets (constant across chunks) ----
    int stoff[4];
    #pragma unroll
    for (int uu = 0; uu < 4; ++uu) {
        int u = uu * 256 + t;
        int row = u >> 5, slot = u & 31;
        stoff[uu] = row * 256 + ((slot ^ (row & 7)) << 3);
    }
    const float4* gh = (const float4*)codh;   // 16B granules, [code][slot] linear
    const float4* gl = (const float4*)codl;

    // ---- stage chunk 0 into buf 0 ----
    float4 sth[4], stl[4];
    #pragma unroll
    for (int uu = 0; uu < 4; ++uu) {
        int u = uu * 256 + t;
        sth[uu] = gh[u];
        stl[uu] = gl[u];
    }
    #pragma unroll
    for (int uu = 0; uu < 4; ++uu) {
        *(float4*)(&Bh[0][stoff[uu]]) = sth[uu];
        *(float4*)(&Bl[0][stoff[uu]]) = stl[uu];
    }
    __syncthreads();

    float bv[2][4]; int bi[2][4];
    #pragma unroll
    for (int mt = 0; mt < 2; ++mt)
        #pragma unroll
        for (int r = 0; r < 4; ++r) { bv[mt][r] = 3.0e38f; bi[mt][r] = 0; }

    int c = 0;
    for (int ch = 0; ch < 32; ++ch) {
        // prefetch next chunk into registers (hides L2 latency under MFMA phase)
        if (ch < 31) {
            #pragma unroll
            for (int uu = 0; uu < 4; ++uu) {
                int u = (ch + 1) * 1024 + uu * 256 + t;
                sth[uu] = gh[u];
                stl[uu] = gl[u];
            }
        }
        // compute on buf[c]
        f32x4 acc[2][2];
        #pragma unroll
        for (int i = 0; i < 2; ++i)
            #pragma unroll
            for (int j = 0; j < 2; ++j) acc[i][j] = (f32x4){0.f, 0.f, 0.f, 0.f};
        #pragma unroll
        for (int nt = 0; nt < 2; ++nt) {
            int code = nt * 16 + lm;              // row within chunk
            int cbase = code * 256;
            int cx = code & 7;
            #pragma unroll
            for (int ks = 0; ks < 8; ++ks) {
                int slot = ks * 4 + lq;
                int off = cbase + (((slot ^ cx)) << 3);
                bf16x8 bh = *(const bf16x8*)(&Bh[c][off]);
                bf16x8 bl = *(const bf16x8*)(&Bl[c][off]);
                acc[0][nt] = MFMA16(ah[0][ks], bh, acc[0][nt]);
                acc[0][nt] = MFMA16(ah[0][ks], bl, acc[0][nt]);
                acc[0][nt] = MFMA16(al[0][ks], bh, acc[0][nt]);
                acc[1][nt] = MFMA16(ah[1][ks], bh, acc[1][nt]);
                acc[1][nt] = MFMA16(ah[1][ks], bl, acc[1][nt]);
                acc[1][nt] = MFMA16(al[1][ks], bh, acc[1][nt]);
            }
        }
        #pragma unroll
        for (int nt = 0; nt < 2; ++nt) {
            int code = ch * 32 + nt * 16 + lm;
            float cn = cnorm[code];
            #pragma unroll
            for (int mt = 0; mt < 2; ++mt)
                #pragma unroll
                for (int r = 0; r < 4; ++r) {
                    float d = cn - 2.f * acc[mt][nt][r];
                    if (d < bv[mt][r]) { bv[mt][r] = d; bi[mt][r] = code; }
                }
        }
        // write prefetched chunk into the other buffer
        if (ch < 31) {
            #pragma unroll
            for (int uu = 0; uu < 4; ++uu) {
                *(float4*)(&Bh[c ^ 1][stoff[uu]]) = sth[uu];
                *(float4*)(&Bl[c ^ 1][stoff[uu]]) = stl[uu];
            }
            __syncthreads();
        }
        c ^= 1;
    }

    // reduce over the 16 column-lanes (lexicographic: value, then smaller index)
    #pragma unroll
    for (int mt = 0; mt < 2; ++mt)
        #pragma unroll
        for (int r = 0; r < 4; ++r) {
            float v = bv[mt][r]; int i = bi[mt][r];
            #pragma unroll
            for (int mask = 1; mask <= 8; mask <<= 1) {
                float ov = __shfl_xor(v, mask);
                int oi = __shfl_xor(i, mask);
                if (ov < v || (ov == v && oi < i)) { v = ov; i = oi; }
            }
            bv[mt][r] = v; bi[mt][r] = i;
        }
    // NO GLOBAL ATOMICS: write enc + per-wave loss partial only.
    float lp = 0.f;
    if (lm == 0) {
        #pragma unroll
        for (int mt = 0; mt < 2; ++mt)
            #pragma unroll
            for (int r = 0; r < 4; ++r) {
                int row_loc = mt * 16 + lq * 4 + r;
                enc[r0 + row_loc] = bi[mt][r];
                lp += fnbuf[wv * 32 + row_loc] + bv[mt][r];
            }
    }
    lp += __shfl_xor(lp, 16);
    lp += __shfl_xor(lp, 32);
    if (lane == 0) lpart[blockIdx.x * 4 + wv] = lp;
}

// ============================ hist: partial histograms of enc (LDS atomics only) ============================
__global__ __launch_bounds__(256) void hist_kernel(
    const int* __restrict__ enc, int* __restrict__ hpart)
{
    __shared__ int lh[1024];
    const int t = threadIdx.x, b = blockIdx.x;
    #pragma unroll
    for (int i = 0; i < 4; ++i) lh[t + i * 256] = 0;
    __syncthreads();
    #pragma unroll
    for (int i = 0; i < 4; ++i) {
        int e = enc[b * 1024 + t + i * 256];
        atomicAdd(&lh[e], 1);               // LDS atomic: per-CU, fast
    }
    __syncthreads();
    #pragma unroll
    for (int i = 0; i < 4; ++i)
        hpart[b * 1024 + t + i * 256] = lh[t + i * 256];
}

// ============================ prep2: fc1 weight slices split (K-inner-32 layout) ============================
// f1[pos][kb][out][32]: element (pos,o,c) at ((pos*8+(c>>5))*512+o)*32+(c&31)
__global__ __launch_bounds__(256) void prep2_kernel(
    const float* __restrict__ fc1w,
    unsigned short* __restrict__ f1h, unsigned short* __restrict__ f1l)
{
    int i = blockIdx.x * 256 + threadIdx.x;   // 2,097,152
    int pos = i >> 17, rem = i & 131071, o = rem >> 8, c = rem & 255;
    float v = fc1w[(size_t)o * 4096 + c * 16 + pos];
    unsigned short h, l; split2(v, &h, &l);
    int d = ((pos * 8 + (c >> 5)) * 512 + o) * 32 + (c & 31);
    f1h[d] = h; f1l[d] = l;
}

// ============================ lut: LUT[pos][code][out] = codes . W1-slice ============================
// A from codT [kb][code][32], B from f1 [pos][kb][out][32]: both coalesced.
__global__ __launch_bounds__(256, 2) void lut_kernel(
    const unsigned short* __restrict__ codTh, const unsigned short* __restrict__ codTl,
    const unsigned short* __restrict__ f1h, const unsigned short* __restrict__ f1l,
    float* __restrict__ lut)
{
    const int t = threadIdx.x, b = blockIdx.x;
    const int pos = b >> 5, sub = b & 31, mblk = sub >> 2, nblk = sub & 3;
    const int wv = t >> 6, lane = t & 63, lq = lane >> 4, lm = lane & 15;
    const int mh = wv >> 1, nh = wv & 1;
    f32x4 acc[4][4];
    #pragma unroll
    for (int i = 0; i < 4; ++i)
        #pragma unroll
        for (int j = 0; j < 4; ++j) acc[i][j] = (f32x4){0.f, 0.f, 0.f, 0.f};
    #pragma unroll
    for (int ks = 0; ks < 8; ++ks) {
        bf16x8 ah[4], al[4];
        #pragma unroll
        for (int mt = 0; mt < 4; ++mt) {
            int code = mblk * 128 + mh * 64 + mt * 16 + lm;
            ah[mt] = *(const bf16x8*)(codTh + (size_t)(ks * 1024 + code) * 32 + lq * 8);
            al[mt] = *(const bf16x8*)(codTl + (size_t)(ks * 1024 + code) * 32 + lq * 8);
        }
        #pragma unroll
        for (int nt = 0; nt < 4; ++nt) {
            int o = nblk * 128 + nh * 64 + nt * 16 + lm;
            bf16x8 bh = *(const bf16x8*)(f1h + (size_t)((pos * 8 + ks) * 512 + o) * 32 + lq * 8);
            bf16x8 bl = *(const bf16x8*)(f1l + (size_t)((pos * 8 + ks) * 512 + o) * 32 + lq * 8);
            #pragma unroll
            for (int mt = 0; mt < 4; ++mt) {
                acc[mt][nt] = MFMA16(ah[mt], bh, acc[mt][nt]);
                acc[mt][nt] = MFMA16(ah[mt], bl, acc[mt][nt]);
                acc[mt][nt] = MFMA16(al[mt], bh, acc[mt][nt]);
            }
        }
    }
    #pragma unroll
    for (int nt = 0; nt < 4; ++nt) {
        int o = nblk * 128 + nh * 64 + nt * 16 + lm;
        #pragma unroll
        for (int mt = 0; mt < 4; ++mt)
            #pragma unroll
            for (int r = 0; r < 4; ++r) {
                int code = mblk * 128 + mh * 64 + mt * 16 + lq * 4 + r;
                lut[((size_t)pos * 1024 + code) * 512 + o] = acc[mt][nt][r];
            }
    }
}

// ============================ hsum: h = gelu(b1 + sum_pos LUT[pos][enc]) ============================
__device__ inline float gelu_tanh(float x) {
    float x3 = x * x * x;
    float u = 0.7978845608028654f * (x + 0.044715f * x3);
    return 0.5f * x * (1.0f + tanhf(u));
}

__global__ __launch_bounds__(256) void hsum_kernel(
    const int* __restrict__ enc, const float* __restrict__ lut,
    const float* __restrict__ fc1b, float* __restrict__ h)
{
    __shared__ int e[16];
    const int t = threadIdx.x, img = blockIdx.x;
    if (t < 16) e[t] = enc[img * 16 + t];
    __syncthreads();
    for (int rep = 0; rep < 2; ++rep) {
        int o = rep * 256 + t;
        float acc = fc1b[o];
        #pragma unroll
        for (int p = 0; p < 16; ++p)
            acc += lut[((size_t)p * 1024 + e[p]) * 512 + o];
        h[(size_t)img * 512 + o] = gelu_tanh(acc);
    }
}

// ============================ fc2 ============================
__global__ __launch_bounds__(256) void fc2_kernel(
    const float* __restrict__ h, const float* __restrict__ fc2w,
    const float* __restrict__ fc2b, float* __restrict__ out)
{
    __shared__ float ws2[10 * 512];
    const int t = threadIdx.x;
    for (int i = t; i < 5120; i += 256) ws2[i] = fc2w[i];
    __syncthreads();
    const int lane = t & 63, wv = t >> 6;
    const int n = blockIdx.x * 4 + wv;
    float acc[10];
    #pragma unroll
    for (int j = 0; j < 10; ++j) acc[j] = 0.f;
    #pragma unroll
    for (int i = 0; i < 8; ++i) {
        float hv = h[(size_t)n * 512 + lane + 64 * i];
        #pragma unroll
        for (int j = 0; j < 10; ++j) acc[j] += hv * ws2[j * 512 + lane + 64 * i];
    }
    #pragma unroll
    for (int j = 0; j < 10; ++j) {
        float v = acc[j];
        for (int off = 32; off; off >>= 1) v += __shfl_down(v, off);
        if (lane == 0) out[(size_t)n * 10 + j] = v + fc2b[j];
    }
}

// ============================ finalize ============================
__global__ __launch_bounds__(256) void finalize_kernel(
    const int* __restrict__ hpart, const float* __restrict__ lpart,
    const int* __restrict__ idxp, float* __restrict__ out)
{
    __shared__ float red[256], red2[256];
    const int t = threadIdx.x;
    const int Kc = (idxp[0] == 0) ? 512 : 1024;
    float s = 0.f;
    for (int k = t; k < Kc; k += 256) {
        int c = 0;
        for (int p = 0; p < 64; ++p) c += hpart[p * 1024 + k];
        float pr = (float)c * (1.0f / 65536.0f);
        s += pr * logf(pr + 1e-10f);
    }
    float ls = 0.f;
    for (int j = t; j < 2048; j += 256) ls += lpart[j];
    red[t] = s; red2[t] = ls;
    __syncthreads();
    for (int o = 128; o; o >>= 1) {
        if (t < o) { red[t] += red[t + o]; red2[t] += red2[t + o]; }
        __syncthreads();
    }
    if (t == 0) {
        out[40960] = red2[0] * (1.25f / 16777216.0f);   // (1+0.25) * mean over 65536*256
        out[40961] = expf(-red[0]);
    }
}

// ============================ launch ============================
extern "C" void kernel_launch(void* const* d_in, const int* in_sizes, int n_in,
                              void* d_out, int out_size, void* d_ws, size_t ws_size,
                              hipStream_t stream)
{
    const float* x     = (const float*)d_in[0];
    const float* w1    = (const float*)d_in[1];
    const float* b1    = (const float*)d_in[2];
    const float* w2    = (const float*)d_in[3];
    const float* b2    = (const float*)d_in[4];
    const float* w3    = (const float*)d_in[5];
    const float* b3    = (const float*)d_in[6];
    const float* code0 = (const float*)d_in[7];
    const float* code1 = (const float*)d_in[8];
    const float* fc1w  = (const float*)d_in[9];
    const float* fc1b  = (const float*)d_in[10];
    const float* fc2w  = (const float*)d_in[11];
    const float* fc2b  = (const float*)d_in[12];
    const int*   idxp  = (const int*)d_in[13];
    float* out = (float*)d_out;
    char* ws = (char*)d_ws;

    unsigned short* w1sh = (unsigned short*)(ws + OFF_W1SH);
    unsigned short* w1sl = (unsigned short*)(ws + OFF_W1SL);
    unsigned short* w2sh = (unsigned short*)(ws + OFF_W2SH);
    unsigned short* w2sl = (unsigned short*)(ws + OFF_W2SL);
    unsigned short* w3sh = (unsigned short*)(ws + OFF_W3SH);
    unsigned short* w3sl = (unsigned short*)(ws + OFF_W3SL);
    unsigned short* codh = (unsigned short*)(ws + OFF_CODH);
    unsigned short* codl = (unsigned short*)(ws + OFF_CODL);
    unsigned short* codTh= (unsigned short*)(ws + OFF_CODTH);
    unsigned short* codTl= (unsigned short*)(ws + OFF_CODTL);
    float* cnorm = (float*)(ws + OFF_CNORM);
    int*   enc   = (int*)(ws + OFF_ENC);
    unsigned short* y2h = (unsigned short*)(ws + OFF_BIG);
    unsigned short* y2l = (unsigned short*)(ws + OFF_BIG + 67108864);
    unsigned short* fh  = (unsigned short*)(ws + OFF_FLATS);
    unsigned short* fl  = (unsigned short*)(ws + OFF_FLATS + 33554432);
    // post-conv3 aliases (y2 region dead):
    float* lut = (float*)(ws + OFF_BIG);
    float* h   = (float*)(ws + OFF_BIG + 33554432);
    int*   hpart = (int*)(ws + OFF_HPART);
    float* lpart = (float*)(ws + OFF_LPART);
    // post-vq aliases (flat region dead):
    unsigned short* f1h = (unsigned short*)(ws + OFF_FLATS);
    unsigned short* f1l = (unsigned short*)(ws + OFF_FLATS + 8388608);

    prep1_kernel<<<2481, 256, 0, stream>>>(w1, w2, w3, code0, code1, idxp,
                                           w1sh, w1sl, w2sh, w2sl, w3sh, w3sl,
                                           codh, codl, codTh, codTl, cnorm);
    conv12_kernel<<<8192, 256, 0, stream>>>(x, w1sh, w1sl, b1, w2sh, w2sl, b2, y2h, y2l);
    conv3_kernel<<<512, 256, 0, stream>>>(y2h, y2l, w3sh, w3sl, b3, fh, fl);
    vq_kernel<<<512, 256, 0, stream>>>(fh, fl, codh, codl, cnorm, enc, lpart);
    hist_kernel<<<64, 256, 0, stream>>>(enc, hpart);
    prep2_kernel<<<8192, 256, 0, stream>>>(fc1w, f1h, f1l);
    lut_kernel<<<512, 256, 0, stream>>>(codTh, codTl, f1h, f1l, lut);
    hsum_kernel<<<4096, 256, 0, stream>>>(enc, lut, fc1b, h);
    fc2_kernel<<<1024, 256, 0, stream>>>(h, fc2w, fc2b, out);
    finalize_kernel<<<1, 256, 0, stream>>>(hpart, lpart, idxp, out);
}

// Round 13
// 746.790 us; speedup vs baseline: 2.4657x; 1.0465x over previous
//
#include <hip/hip_runtime.h>
#include <math.h>

// ============================ MFMA types/helpers ============================
typedef short bf16x8 __attribute__((ext_vector_type(8)));   // 8 bf16 (4 VGPRs)
typedef float f32x4 __attribute__((ext_vector_type(4)));

#define MFMA16(a, b, c) __builtin_amdgcn_mfma_f32_16x16x32_bf16((a), (b), (c), 0, 0, 0)

__device__ inline unsigned short bf16_rn(float x) {
    unsigned u = __float_as_uint(x);
    unsigned r = u + 0x7FFFu + ((u >> 16) & 1u);
    return (unsigned short)(r >> 16);
}
__device__ inline float bf16_to_f(unsigned short h) {
    return __uint_as_float(((unsigned)h) << 16);
}
__device__ inline void split2(float x, unsigned short* hp, unsigned short* lp) {
    unsigned short h = bf16_rn(x);
    *hp = h;
    *lp = bf16_rn(x - bf16_to_f(h));
}

// ============================ workspace layout (bytes) ============================
static constexpr size_t OFF_W1SH  = 0;           // [64co][32k] shorts (K-inner)
static constexpr size_t OFF_W1SL  = 4096;
static constexpr size_t OFF_W2SH  = 8192;        // [18kb][128co][32] shorts
static constexpr size_t OFF_W2SL  = 155648;
static constexpr size_t OFF_W3SH  = 303104;      // [36kb][256co][32] shorts
static constexpr size_t OFF_W3SL  = 892928;
static constexpr size_t OFF_CODH  = 1482752;     // [1024][256] shorts (rows>=Kc zero) - vq layout
static constexpr size_t OFF_CODL  = 2007040;
static constexpr size_t OFF_CNORM = 2531328;     // [1024] f32 (3e38 for >=Kc)
static constexpr size_t OFF_COUNTS= 2535424;     // legacy
static constexpr size_t OFF_LOSS  = 2539520;     // legacy
static constexpr size_t OFF_ENC   = 2539776;     // [65536] int
static constexpr size_t OFF_BIG   = 2801920;     // y2h(67108864)+y2l(67108864)
                                                 // post-conv3 reuse: LUT f32 (33554432) + h f32 (8388608)
static constexpr size_t OFF_HPART = OFF_BIG + 50331648;   // [64][1024] int (256KB)
static constexpr size_t OFF_LPART = OFF_HPART + 262144;   // [2048] f32 (8KB)
static constexpr size_t OFF_FLATS = 137019648;   // fh(33554432)+fl(33554432)
                                                 // post-vq reuse: f1h(8388608)+f1l(8388608) [kb layout]
static constexpr size_t OFF_CODTH = 204128512;   // [8kb][1024code][32] shorts (524288 B)
static constexpr size_t OFF_CODTL = 204652800;   // total 205,177,088 < 212,515,840 proven

// ============================ prep1: weight/code splits ============================
__global__ __launch_bounds__(256) void prep1_kernel(
    const float* __restrict__ w1, const float* __restrict__ w2,
    const float* __restrict__ w3, const float* __restrict__ code0,
    const float* __restrict__ code1, const int* __restrict__ idxp,
    unsigned short* __restrict__ w1sh, unsigned short* __restrict__ w1sl,
    unsigned short* __restrict__ w2sh, unsigned short* __restrict__ w2sl,
    unsigned short* __restrict__ w3sh, unsigned short* __restrict__ w3sl,
    unsigned short* __restrict__ codh, unsigned short* __restrict__ codl,
    unsigned short* __restrict__ codTh, unsigned short* __restrict__ codTl,
    float* __restrict__ cnorm)
{
    int i = blockIdx.x * 256 + threadIdx.x;
    const int Kc = (idxp[0] == 0) ? 512 : 1024;
    if (i < 2048) {                           // w1s [co][32], k=(kh*3+kw)*3+ci
        int co = i >> 5, k = i & 31;
        float v = 0.f;
        if (k < 27) {
            int khw = k / 3, ci = k - khw * 3;
            v = w1[(co * 3 + ci) * 9 + khw];
        }
        unsigned short h, l; split2(v, &h, &l);
        w1sh[i] = h; w1sl[i] = l; return;
    }
    i -= 2048;
    if (i < 73728) {                          // w2s: k=khw*64+ci -> [k>>5][co][k&31]
        int co = i / 576, k = i - co * 576;
        int khw = k >> 6, ci = k & 63;
        float v = w2[(co * 64 + ci) * 9 + khw];
        unsigned short h, l; split2(v, &h, &l);
        int d = ((k >> 5) * 128 + co) * 32 + (k & 31);
        w2sh[d] = h; w2sl[d] = l; return;
    }
    i -= 73728;
    if (i < 294912) {                         // w3s: k=khw*128+ci -> [k>>5][co][k&31]
        int co = i / 1152, k = i - co * 1152;
        int khw = k >> 7, ci = k & 127;
        float v = w3[(co * 128 + ci) * 9 + khw];
        unsigned short h, l; split2(v, &h, &l);
        int d = ((k >> 5) * 256 + co) * 32 + (k & 31);
        w3sh[d] = h; w3sl[d] = l; return;
    }
    i -= 294912;
    if (i < 262144) {                         // codes [code][256] + transposed [c>>5][code][c&31]
        int code = i >> 8, c = i & 255;
        float v = 0.f;
        if (code < Kc) v = (code < 512) ? code0[code * 256 + c]
                                        : code1[(code - 512) * 256 + c];
        unsigned short h, l; split2(v, &h, &l);
        codh[i] = h; codl[i] = l;
        int d = ((c >> 5) * 1024 + code) * 32 + (c & 31);
        codTh[d] = h; codTl[d] = l; return;
    }
    i -= 262144;
    if (i < 1024) {                           // cnorm (exact fp32)
        float s;
        if (i < Kc) {
            const float* c = (i < 512) ? code0 + (size_t)i * 256
                                       : code1 + (size_t)(i - 512) * 256;
            s = 0.f;
            for (int k = 0; k < 256; ++k) s += c[k] * c[k];
        } else s = 3.0e38f;
        cnorm[i] = s; return;
    }
}

// ============================ conv12: fused conv1+conv2 (split-bf16 MFMA) ============================
// ROUND 13: LDS cut 62496 -> 44064 B (3 blocks/CU, was 2) by overlapping the
// conv1 im2col A-tile into the y1 region. Ordering change: conv1 pre-loads
// all 18 A-fragments into registers, barrier, THEN pad-zeroing + MFMA +
// y1 writes (which may overwrite the A region). launch_bounds(256,3) caps
// VGPR at ~170 (live ~160). Math/layout/outputs unchanged.
// LDS map: [0,44064) = y1h(22032)+y1l(22032); xsp f32[3][34][34] aliases
// [0,13872); A-tile Ah1(9216)+Al1(9216) aliases [13872,32304).
__global__ __launch_bounds__(256, 3) void conv12_kernel(
    const float* __restrict__ x,
    const unsigned short* __restrict__ w1sh, const unsigned short* __restrict__ w1sl,
    const float* __restrict__ b1,
    const unsigned short* __restrict__ w2sh, const unsigned short* __restrict__ w2sl,
    const float* __restrict__ b2,
    unsigned short* __restrict__ y2h, unsigned short* __restrict__ y2l)
{
    __shared__ __align__(16) char smem[44064];
    float* xsp = (float*)smem;
    unsigned short* y1h = (unsigned short*)smem;
    unsigned short* y1l = (unsigned short*)(smem + 22032);
    unsigned short* Ah1 = (unsigned short*)(smem + 13872);
    unsigned short* Al1 = (unsigned short*)(smem + 23088);
    const int t = threadIdx.x;
    const int n = blockIdx.x >> 1, hh = blockIdx.x & 1;
    const int wv = t >> 6, lane = t & 63, lq = lane >> 4, lm = lane & 15;

    // ---- load x into padded LDS ----
    for (int i = t; i < 3468; i += 256) xsp[i] = 0.f;
    __syncthreads();
    const float* xn = x + (size_t)n * 3072;
    for (int i = t; i < 768; i += 256) {
        float4 v = ((const float4*)xn)[i];
        int ci = i >> 8, rem = i & 255, ih = rem >> 3, iw = (rem & 7) << 2;
        float* d = xsp + (size_t)(ci * 34 + ih + 1) * 34 + iw + 1;
        d[0] = v.x; d[1] = v.y; d[2] = v.z; d[3] = v.w;
    }
    __syncthreads();

    // ---- conv1 im2col (xsp -> A tile; disjoint regions) ----
    for (int i = t; i < 4608; i += 256) {
        int px = i >> 5, k = i & 31;
        int l = px >> 4, ow = px & 15;
        float v = 0.f;
        if (k < 27 && !(hh == 0 && l == 0)) {
            int khw = k / 3, ci = k - khw * 3;
            int kh = khw / 3, kw = khw - kh * 3;
            int xr = 16 * hh - 2 + 2 * l + kh;      // padded row idx
            int xc = 2 * ow + kw;                   // padded col idx
            v = xsp[(size_t)(ci * 34 + xr) * 34 + xc];
        }
        unsigned short vh, vl; split2(v, &vh, &vl);
        int q = k >> 3, j = k & 7;
        Ah1[(q * 144 + px) * 8 + j] = vh;
        Al1[(q * 144 + px) * 8 + j] = vl;
    }
    __syncthreads();

    // ---- conv1: pre-load ALL A fragments into registers (A region about to die) ----
    bf16x8 a1h[9], a1l[9];
    #pragma unroll
    for (int mt = 0; mt < 9; ++mt) {
        a1h[mt] = *(const bf16x8*)(Ah1 + (lq * 144 + mt * 16 + lm) * 8);
        a1l[mt] = *(const bf16x8*)(Al1 + (lq * 144 + mt * 16 + lm) * 8);
    }
    __syncthreads();   // all waves hold A in regs; y1 region (incl. A alias) writable

    // ---- zero y1 pads: row l==0 fully + column c==0 of rows 1..8 ----
    {
        unsigned* zh = (unsigned*)y1h; unsigned* zl = (unsigned*)y1l;
        for (int i = t; i < 612; i += 256) { zh[i] = 0u; zl[i] = 0u; }
        for (int i = t; i < 288; i += 256) {
            int l = 1 + i / 36, d = i - (l - 1) * 36;
            zh[l * 612 + d] = 0u; zl[l * 612 + d] = 0u;
        }
    }

    // ---- conv1 via MFMA (from registers) + y1 writes ----
    {
        f32x4 acc[9];
        #pragma unroll
        for (int mt = 0; mt < 9; ++mt) acc[mt] = (f32x4){0.f, 0.f, 0.f, 0.f};
        int co = wv * 16 + lm;
        bf16x8 bh = *(const bf16x8*)(w1sh + co * 32 + lq * 8);
        bf16x8 bl = *(const bf16x8*)(w1sl + co * 32 + lq * 8);
        #pragma unroll
        for (int mt = 0; mt < 9; ++mt) {
            acc[mt] = MFMA16(a1h[mt], bh, acc[mt]);
            acc[mt] = MFMA16(a1h[mt], bl, acc[mt]);
            acc[mt] = MFMA16(a1l[mt], bh, acc[mt]);
        }
        float bias = b1[co];
        #pragma unroll
        for (int mt = 0; mt < 9; ++mt) {
            #pragma unroll
            for (int r = 0; r < 4; ++r) {
                int px = mt * 16 + lq * 4 + r;
                int l = px >> 4, ow = px & 15;
                if (hh == 0 && l == 0) continue;
                float v = fmaxf(acc[mt][r] + bias, 0.f);
                unsigned short vh, vl; split2(v, &vh, &vl);
                y1h[(l * 17 + ow + 1) * 72 + co] = vh;
                y1l[(l * 17 + ow + 1) * 72 + co] = vl;
            }
        }
    }
    __syncthreads();

    // ---- conv2 via MFMA (B loads K-inner-32: contiguous 1KB per instr) ----
    {
        const int mt2 = wv >> 1, nh = wv & 1;
        f32x4 acc[4];
        #pragma unroll
        for (int i = 0; i < 4; ++i) acc[i] = (f32x4){0.f, 0.f, 0.f, 0.f};
        int px = mt2 * 16 + lm;
        int ohl = px >> 3, ow2 = px & 7;
        #pragma unroll
        for (int ks = 0; ks < 18; ++ks) {
            int khw = ks >> 1;
            int kh = khw / 3, kw = khw - kh * 3;
            int ci0 = (ks & 1) * 32 + lq * 8;
            int l = 2 * ohl + kh, c = 2 * ow2 + kw;
            bf16x8 ah = *(const bf16x8*)(y1h + (l * 17 + c) * 72 + ci0);
            bf16x8 al = *(const bf16x8*)(y1l + (l * 17 + c) * 72 + ci0);
            #pragma unroll
            for (int nt = 0; nt < 4; ++nt) {
                int co = nh * 64 + nt * 16 + lm;
                bf16x8 bh = *(const bf16x8*)(w2sh + (ks * 128 + co) * 32 + lq * 8);
                bf16x8 bl = *(const bf16x8*)(w2sl + (ks * 128 + co) * 32 + lq * 8);
                acc[nt] = MFMA16(ah, bh, acc[nt]);
                acc[nt] = MFMA16(ah, bl, acc[nt]);
                acc[nt] = MFMA16(al, bh, acc[nt]);
            }
        }
        #pragma unroll
        for (int nt = 0; nt < 4; ++nt) {
            int co = nh * 64 + nt * 16 + lm;
            float bias = b2[co];
            #pragma unroll
            for (int r = 0; r < 4; ++r) {
                int pxr = mt2 * 16 + lq * 4 + r;
                int ohr = pxr >> 3, owr = pxr & 7;
                float v = fmaxf(acc[nt][r] + bias, 0.f);
                unsigned short vh, vl; split2(v, &vh, &vl);
                size_t o = ((size_t)n * 64 + (hh * 4 + ohr) * 8 + owr) * 128 + co;
                y2h[o] = vh; y2l[o] = vl;
            }
        }
    }
}

// ============================ conv3: implicit GEMM 128px x 256co, K=1152 ============================
__global__ __launch_bounds__(256, 2) void conv3_kernel(
    const unsigned short* __restrict__ y2h, const unsigned short* __restrict__ y2l,
    const unsigned short* __restrict__ w3sh, const unsigned short* __restrict__ w3sl,
    const float* __restrict__ b3,
    unsigned short* __restrict__ fh, unsigned short* __restrict__ fl)
{
    __shared__ __align__(16) unsigned short Ah[4 * 128 * 8];   // [q][px][8]
    __shared__ __align__(16) unsigned short Al[4 * 128 * 8];
    const int t = threadIdx.x, b = blockIdx.x;
    const int wv = t >> 6, lane = t & 63, lq = lane >> 4, lm = lane & 15;
    const int mh = wv >> 1, nh = wv & 1;
    f32x4 acc[4][8];
    #pragma unroll
    for (int i = 0; i < 4; ++i)
        #pragma unroll
        for (int j = 0; j < 8; ++j) acc[i][j] = (f32x4){0.f, 0.f, 0.f, 0.f};
    const int gpx = t >> 1, gsel = t & 1;
    const int gimg = b * 8 + (gpx >> 4);
    const int gp = gpx & 15, goh = gp >> 2, gow = gp & 3;
    const unsigned short* gsrc = gsel ? y2l : y2h;
    unsigned short* gdst = gsel ? Al : Ah;

    for (int ks = 0; ks < 36; ++ks) {
        __syncthreads();
        {
            int khw = ks >> 2;
            int kh = khw / 3, kw = khw - kh * 3;
            int ci0 = (ks & 3) * 32;
            int ih = 2 * goh + kh - 1, iw = 2 * gow + kw - 1;
            if (ih >= 0 && ih < 8 && iw >= 0 && iw < 8) {
                const unsigned short* s = gsrc + ((size_t)gimg * 64 + ih * 8 + iw) * 128 + ci0;
                #pragma unroll
                for (int qq = 0; qq < 4; ++qq)
                    *(bf16x8*)(gdst + (qq * 128 + gpx) * 8) = *(const bf16x8*)(s + qq * 8);
            } else {
                #pragma unroll
                for (int qq = 0; qq < 4; ++qq)
                    *(bf16x8*)(gdst + (qq * 128 + gpx) * 8) = (bf16x8){0, 0, 0, 0, 0, 0, 0, 0};
            }
        }
        __syncthreads();
        bf16x8 ah[4], al[4];
        #pragma unroll
        for (int mt = 0; mt < 4; ++mt) {
            int mloc = mh * 64 + mt * 16 + lm;
            ah[mt] = *(const bf16x8*)(Ah + (lq * 128 + mloc) * 8);
            al[mt] = *(const bf16x8*)(Al + (lq * 128 + mloc) * 8);
        }
        #pragma unroll
        for (int nt = 0; nt < 8; ++nt) {
            int co = nh * 128 + nt * 16 + lm;
            bf16x8 bh = *(const bf16x8*)(w3sh + (size_t)(ks * 256 + co) * 32 + lq * 8);
            bf16x8 bl = *(const bf16x8*)(w3sl + (size_t)(ks * 256 + co) * 32 + lq * 8);
            #pragma unroll
            for (int mt = 0; mt < 4; ++mt) {
                acc[mt][nt] = MFMA16(ah[mt], bh, acc[mt][nt]);
                acc[mt][nt] = MFMA16(ah[mt], bl, acc[mt][nt]);
                acc[mt][nt] = MFMA16(al[mt], bh, acc[mt][nt]);
            }
        }
    }
    #pragma unroll
    for (int nt = 0; nt < 8; ++nt) {
        int co = nh * 128 + nt * 16 + lm;
        float bias = b3[co];
        #pragma unroll
        for (int mt = 0; mt < 4; ++mt) {
            #pragma unroll
            for (int r = 0; r < 4; ++r) {
                int mloc = mh * 64 + mt * 16 + lq * 4 + r;
                size_t row = (size_t)b * 128 + mloc;
                float v = fmaxf(acc[mt][nt][r] + bias, 0.f);
                unsigned short vh, vl; split2(v, &vh, &vl);
                fh[row * 256 + co] = vh;
                fl[row * 256 + co] = vl;
            }
        }
    }
}

// ============================ vq: fused distance GEMM + argmin + loss ============================
// (R11's atomic-free version -- confirmed fast. Unchanged.)
__global__ __launch_bounds__(256, 2) void vq_kernel(
    const unsigned short* __restrict__ fh, const unsigned short* __restrict__ fl,
    const unsigned short* __restrict__ codh, const unsigned short* __restrict__ codl,
    const float* __restrict__ cnorm, int* __restrict__ enc,
    float* __restrict__ lpart)
{
    __shared__ __align__(16) unsigned short Bh[2][8192];   // [buf][row(32)][swz slot(32)*8]
    __shared__ __align__(16) unsigned short Bl[2][8192];
    __shared__ float fnbuf[4 * 32];
    const int t = threadIdx.x;
    const int wv = t >> 6, lane = t & 63, lq = lane >> 4, lm = lane & 15;
    const int r0 = blockIdx.x * 128 + wv * 32;

    // ---- A fragments (full K=256) in registers ----
    bf16x8 ah[2][8], al[2][8];
    #pragma unroll
    for (int mt = 0; mt < 2; ++mt)
        #pragma unroll
        for (int ks = 0; ks < 8; ++ks) {
            size_t base = ((size_t)(r0 + mt * 16 + lm)) * 256 + ks * 32 + lq * 8;
            ah[mt][ks] = *(const bf16x8*)(fh + base);
            al[mt][ks] = *(const bf16x8*)(fl + base);
        }
    // ||f||^2 per row (reduce over the 4 k-quads)
    #pragma unroll
    for (int mt = 0; mt < 2; ++mt) {
        float s = 0.f;
        #pragma unroll
        for (int ks = 0; ks < 8; ++ks)
            #pragma unroll
            for (int j = 0; j < 8; ++j) {
                float v = bf16_to_f((unsigned short)ah[mt][ks][j]) +
                          bf16_to_f((unsigned short)al[mt][ks][j]);
                s += v * v;
            }
        s += __shfl_xor(s, 16);
        s += __shfl_xor(s, 32);
        if (lq == 0) fnbuf[wv * 32 + mt * 16 + lm] = s;
    }

    // ---- per-thread staging offsets (constant across chunks) ----
    int stoff[4];
    #pragma unroll
    for (int uu = 0; uu < 4; ++uu) {
        int u = uu * 256 + t;
        int row = u >> 5, slot = u & 31;
        stoff[uu] = row * 256 + ((slot ^ (row & 7)) << 3);
    }
    const float4* gh = (const float4*)codh;   // 16B granules, [code][slot] linear
    const float4* gl = (const float4*)codl;

    // ---- stage chunk 0 into buf 0 ----
    float4 sth[4], stl[4];
    #pragma unroll
    for (int uu = 0; uu < 4; ++uu) {
        int u = uu * 256 + t;
        sth[uu] = gh[u];
        stl[uu] = gl[u];
    }
    #pragma unroll
    for (int uu = 0; uu < 4; ++uu) {
        *(float4*)(&Bh[0][stoff[uu]]) = sth[uu];
        *(float4*)(&Bl[0][stoff[uu]]) = stl[uu];
    }
    __syncthreads();

    float bv[2][4]; int bi[2][4];
    #pragma unroll
    for (int mt = 0; mt < 2; ++mt)
        #pragma unroll
        for (int r = 0; r < 4; ++r) { bv[mt][r] = 3.0e38f; bi[mt][r] = 0; }

    int c = 0;
    for (int ch = 0; ch < 32; ++ch) {
        // prefetch next chunk into registers (hides L2 latency under MFMA phase)
        if (ch < 31) {
            #pragma unroll
            for (int uu = 0; uu < 4; ++uu) {
                int u = (ch + 1) * 1024 + uu * 256 + t;
                sth[uu] = gh[u];
                stl[uu] = gl[u];
            }
        }
        // compute on buf[c]
        f32x4 acc[2][2];
        #pragma unroll
        for (int i = 0; i < 2; ++i)
            #pragma unroll
            for (int j = 0; j < 2; ++j) acc[i][j] = (f32x4){0.f, 0.f, 0.f, 0.f};
        #pragma unroll
        for (int nt = 0; nt < 2; ++nt) {
            int code = nt * 16 + lm;              // row within chunk
            int cbase = code * 256;
            int cx = code & 7;
            #pragma unroll
            for (int ks = 0; ks < 8; ++ks) {
                int slot = ks * 4 + lq;
                int off = cbase + (((slot ^ cx)) << 3);
                bf16x8 bh = *(const bf16x8*)(&Bh[c][off]);
                bf16x8 bl = *(const bf16x8*)(&Bl[c][off]);
                acc[0][nt] = MFMA16(ah[0][ks], bh, acc[0][nt]);
                acc[0][nt] = MFMA16(ah[0][ks], bl, acc[0][nt]);
                acc[0][nt] = MFMA16(al[0][ks], bh, acc[0][nt]);
                acc[1][nt] = MFMA16(ah[1][ks], bh, acc[1][nt]);
                acc[1][nt] = MFMA16(ah[1][ks], bl, acc[1][nt]);
                acc[1][nt] = MFMA16(al[1][ks], bh, acc[1][nt]);
            }
        }
        #pragma unroll
        for (int nt = 0; nt < 2; ++nt) {
            int code = ch * 32 + nt * 16 + lm;
            float cn = cnorm[code];
            #pragma unroll
            for (int mt = 0; mt < 2; ++mt)
                #pragma unroll
                for (int r = 0; r < 4; ++r) {
                    float d = cn - 2.f * acc[mt][nt][r];
                    if (d < bv[mt][r]) { bv[mt][r] = d; bi[mt][r] = code; }
                }
        }
        // write prefetched chunk into the other buffer
        if (ch < 31) {
            #pragma unroll
            for (int uu = 0; uu < 4; ++uu) {
                *(float4*)(&Bh[c ^ 1][stoff[uu]]) = sth[uu];
                *(float4*)(&Bl[c ^ 1][stoff[uu]]) = stl[uu];
            }
            __syncthreads();
        }
        c ^= 1;
    }

    // reduce over the 16 column-lanes (lexicographic: value, then smaller index)
    #pragma unroll
    for (int mt = 0; mt < 2; ++mt)
        #pragma unroll
        for (int r = 0; r < 4; ++r) {
            float v = bv[mt][r]; int i = bi[mt][r];
            #pragma unroll
            for (int mask = 1; mask <= 8; mask <<= 1) {
                float ov = __shfl_xor(v, mask);
                int oi = __shfl_xor(i, mask);
                if (ov < v || (ov == v && oi < i)) { v = ov; i = oi; }
            }
            bv[mt][r] = v; bi[mt][r] = i;
        }
    // NO GLOBAL ATOMICS: write enc + per-wave loss partial only.
    float lp = 0.f;
    if (lm == 0) {
        #pragma unroll
        for (int mt = 0; mt < 2; ++mt)
            #pragma unroll
            for (int r = 0; r < 4; ++r) {
                int row_loc = mt * 16 + lq * 4 + r;
                enc[r0 + row_loc] = bi[mt][r];
                lp += fnbuf[wv * 32 + row_loc] + bv[mt][r];
            }
    }
    lp += __shfl_xor(lp, 16);
    lp += __shfl_xor(lp, 32);
    if (lane == 0) lpart[blockIdx.x * 4 + wv] = lp;
}

// ============================ hist: partial histograms of enc (LDS atomics only) ============================
__global__ __launch_bounds__(256) void hist_kernel(
    const int* __restrict__ enc, int* __restrict__ hpart)
{
    __shared__ int lh[1024];
    const int t = threadIdx.x, b = blockIdx.x;
    #pragma unroll
    for (int i = 0; i < 4; ++i) lh[t + i * 256] = 0;
    __syncthreads();
    #pragma unroll
    for (int i = 0; i < 4; ++i) {
        int e = enc[b * 1024 + t + i * 256];
        atomicAdd(&lh[e], 1);               // LDS atomic: per-CU, fast
    }
    __syncthreads();
    #pragma unroll
    for (int i = 0; i < 4; ++i)
        hpart[b * 1024 + t + i * 256] = lh[t + i * 256];
}

// ============================ prep2: fc1 weight slices split (K-inner-32 layout) ============================
// f1[pos][kb][out][32]: element (pos,o,c) at ((pos*8+(c>>5))*512+o)*32+(c&31)
__global__ __launch_bounds__(256) void prep2_kernel(
    const float* __restrict__ fc1w,
    unsigned short* __restrict__ f1h, unsigned short* __restrict__ f1l)
{
    int i = blockIdx.x * 256 + threadIdx.x;   // 2,097,152
    int pos = i >> 17, rem = i & 131071, o = rem >> 8, c = rem & 255;
    float v = fc1w[(size_t)o * 4096 + c * 16 + pos];
    unsigned short h, l; split2(v, &h, &l);
    int d = ((pos * 8 + (c >> 5)) * 512 + o) * 32 + (c & 31);
    f1h[d] = h; f1l[d] = l;
}

// ============================ lut: LUT[pos][code][out] = codes . W1-slice ============================
// A from codT [kb][code][32], B from f1 [pos][kb][out][32]: both coalesced.
__global__ __launch_bounds__(256, 2) void lut_kernel(
    const unsigned short* __restrict__ codTh, const unsigned short* __restrict__ codTl,
    const unsigned short* __restrict__ f1h, const unsigned short* __restrict__ f1l,
    float* __restrict__ lut)
{
    const int t = threadIdx.x, b = blockIdx.x;
    const int pos = b >> 5, sub = b & 31, mblk = sub >> 2, nblk = sub & 3;
    const int wv = t >> 6, lane = t & 63, lq = lane >> 4, lm = lane & 15;
    const int mh = wv >> 1, nh = wv & 1;
    f32x4 acc[4][4];
    #pragma unroll
    for (int i = 0; i < 4; ++i)
        #pragma unroll
        for (int j = 0; j < 4; ++j) acc[i][j] = (f32x4){0.f, 0.f, 0.f, 0.f};
    #pragma unroll
    for (int ks = 0; ks < 8; ++ks) {
        bf16x8 ah[4], al[4];
        #pragma unroll
        for (int mt = 0; mt < 4; ++mt) {
            int code = mblk * 128 + mh * 64 + mt * 16 + lm;
            ah[mt] = *(const bf16x8*)(codTh + (size_t)(ks * 1024 + code) * 32 + lq * 8);
            al[mt] = *(const bf16x8*)(codTl + (size_t)(ks * 1024 + code) * 32 + lq * 8);
        }
        #pragma unroll
        for (int nt = 0; nt < 4; ++nt) {
            int o = nblk * 128 + nh * 64 + nt * 16 + lm;
            bf16x8 bh = *(const bf16x8*)(f1h + (size_t)((pos * 8 + ks) * 512 + o) * 32 + lq * 8);
            bf16x8 bl = *(const bf16x8*)(f1l + (size_t)((pos * 8 + ks) * 512 + o) * 32 + lq * 8);
            #pragma unroll
            for (int mt = 0; mt < 4; ++mt) {
                acc[mt][nt] = MFMA16(ah[mt], bh, acc[mt][nt]);
                acc[mt][nt] = MFMA16(ah[mt], bl, acc[mt][nt]);
                acc[mt][nt] = MFMA16(al[mt], bh, acc[mt][nt]);
            }
        }
    }
    #pragma unroll
    for (int nt = 0; nt < 4; ++nt) {
        int o = nblk * 128 + nh * 64 + nt * 16 + lm;
        #pragma unroll
        for (int mt = 0; mt < 4; ++mt)
            #pragma unroll
            for (int r = 0; r < 4; ++r) {
                int code = mblk * 128 + mh * 64 + mt * 16 + lq * 4 + r;
                lut[((size_t)pos * 1024 + code) * 512 + o] = acc[mt][nt][r];
            }
    }
}

// ============================ hsum: h = gelu(b1 + sum_pos LUT[pos][enc]) ============================
__device__ inline float gelu_tanh(float x) {
    float x3 = x * x * x;
    float u = 0.7978845608028654f * (x + 0.044715f * x3);
    return 0.5f * x * (1.0f + tanhf(u));
}

__global__ __launch_bounds__(256) void hsum_kernel(
    const int* __restrict__ enc, const float* __restrict__ lut,
    const float* __restrict__ fc1b, float* __restrict__ h)
{
    __shared__ int e[16];
    const int t = threadIdx.x, img = blockIdx.x;
    if (t < 16) e[t] = enc[img * 16 + t];
    __syncthreads();
    for (int rep = 0; rep < 2; ++rep) {
        int o = rep * 256 + t;
        float acc = fc1b[o];
        #pragma unroll
        for (int p = 0; p < 16; ++p)
            acc += lut[((size_t)p * 1024 + e[p]) * 512 + o];
        h[(size_t)img * 512 + o] = gelu_tanh(acc);
    }
}

// ============================ fc2 ============================
__global__ __launch_bounds__(256) void fc2_kernel(
    const float* __restrict__ h, const float* __restrict__ fc2w,
    const float* __restrict__ fc2b, float* __restrict__ out)
{
    __shared__ float ws2[10 * 512];
    const int t = threadIdx.x;
    for (int i = t; i < 5120; i += 256) ws2[i] = fc2w[i];
    __syncthreads();
    const int lane = t & 63, wv = t >> 6;
    const int n = blockIdx.x * 4 + wv;
    float acc[10];
    #pragma unroll
    for (int j = 0; j < 10; ++j) acc[j] = 0.f;
    #pragma unroll
    for (int i = 0; i < 8; ++i) {
        float hv = h[(size_t)n * 512 + lane + 64 * i];
        #pragma unroll
        for (int j = 0; j < 10; ++j) acc[j] += hv * ws2[j * 512 + lane + 64 * i];
    }
    #pragma unroll
    for (int j = 0; j < 10; ++j) {
        float v = acc[j];
        for (int off = 32; off; off >>= 1) v += __shfl_down(v, off);
        if (lane == 0) out[(size_t)n * 10 + j] = v + fc2b[j];
    }
}

// ============================ finalize ============================
__global__ __launch_bounds__(256) void finalize_kernel(
    const int* __restrict__ hpart, const float* __restrict__ lpart,
    const int* __restrict__ idxp, float* __restrict__ out)
{
    __shared__ float red[256], red2[256];
    const int t = threadIdx.x;
    const int Kc = (idxp[0] == 0) ? 512 : 1024;
    float s = 0.f;
    for (int k = t; k < Kc; k += 256) {
        int c = 0;
        for (int p = 0; p < 64; ++p) c += hpart[p * 1024 + k];
        float pr = (float)c * (1.0f / 65536.0f);
        s += pr * logf(pr + 1e-10f);
    }
    float ls = 0.f;
    for (int j = t; j < 2048; j += 256) ls += lpart[j];
    red[t] = s; red2[t] = ls;
    __syncthreads();
    for (int o = 128; o; o >>= 1) {
        if (t < o) { red[t] += red[t + o]; red2[t] += red2[t + o]; }
        __syncthreads();
    }
    if (t == 0) {
        out[40960] = red2[0] * (1.25f / 16777216.0f);   // (1+0.25) * mean over 65536*256
        out[40961] = expf(-red[0]);
    }
}

// ============================ launch ============================
extern "C" void kernel_launch(void* const* d_in, const int* in_sizes, int n_in,
                              void* d_out, int out_size, void* d_ws, size_t ws_size,
                              hipStream_t stream)
{
    const float* x     = (const float*)d_in[0];
    const float* w1    = (const float*)d_in[1];
    const float* b1    = (const float*)d_in[2];
    const float* w2    = (const float*)d_in[3];
    const float* b2    = (const float*)d_in[4];
    const float* w3    = (const float*)d_in[5];
    const float* b3    = (const float*)d_in[6];
    const float* code0 = (const float*)d_in[7];
    const float* code1 = (const float*)d_in[8];
    const float* fc1w  = (const float*)d_in[9];
    const float* fc1b  = (const float*)d_in[10];
    const float* fc2w  = (const float*)d_in[11];
    const float* fc2b  = (const float*)d_in[12];
    const int*   idxp  = (const int*)d_in[13];
    float* out = (float*)d_out;
    char* ws = (char*)d_ws;

    unsigned short* w1sh = (unsigned short*)(ws + OFF_W1SH);
    unsigned short* w1sl = (unsigned short*)(ws + OFF_W1SL);
    unsigned short* w2sh = (unsigned short*)(ws + OFF_W2SH);
    unsigned short* w2sl = (unsigned short*)(ws + OFF_W2SL);
    unsigned short* w3sh = (unsigned short*)(ws + OFF_W3SH);
    unsigned short* w3sl = (unsigned short*)(ws + OFF_W3SL);
    unsigned short* codh = (unsigned short*)(ws + OFF_CODH);
    unsigned short* codl = (unsigned short*)(ws + OFF_CODL);
    unsigned short* codTh= (unsigned short*)(ws + OFF_CODTH);
    unsigned short* codTl= (unsigned short*)(ws + OFF_CODTL);
    float* cnorm = (float*)(ws + OFF_CNORM);
    int*   enc   = (int*)(ws + OFF_ENC);
    unsigned short* y2h = (unsigned short*)(ws + OFF_BIG);
    unsigned short* y2l = (unsigned short*)(ws + OFF_BIG + 67108864);
    unsigned short* fh  = (unsigned short*)(ws + OFF_FLATS);
    unsigned short* fl  = (unsigned short*)(ws + OFF_FLATS + 33554432);
    // post-conv3 aliases (y2 region dead):
    float* lut = (float*)(ws + OFF_BIG);
    float* h   = (float*)(ws + OFF_BIG + 33554432);
    int*   hpart = (int*)(ws + OFF_HPART);
    float* lpart = (float*)(ws + OFF_LPART);
    // post-vq aliases (flat region dead):
    unsigned short* f1h = (unsigned short*)(ws + OFF_FLATS);
    unsigned short* f1l = (unsigned short*)(ws + OFF_FLATS + 8388608);

    prep1_kernel<<<2481, 256, 0, stream>>>(w1, w2, w3, code0, code1, idxp,
                                           w1sh, w1sl, w2sh, w2sl, w3sh, w3sl,
                                           codh, codl, codTh, codTl, cnorm);
    conv12_kernel<<<8192, 256, 0, stream>>>(x, w1sh, w1sl, b1, w2sh, w2sl, b2, y2h, y2l);
    conv3_kernel<<<512, 256, 0, stream>>>(y2h, y2l, w3sh, w3sl, b3, fh, fl);
    vq_kernel<<<512, 256, 0, stream>>>(fh, fl, codh, codl, cnorm, enc, lpart);
    hist_kernel<<<64, 256, 0, stream>>>(enc, hpart);
    prep2_kernel<<<8192, 256, 0, stream>>>(fc1w, f1h, f1l);
    lut_kernel<<<512, 256, 0, stream>>>(codTh, codTl, f1h, f1l, lut);
    hsum_kernel<<<4096, 256, 0, stream>>>(enc, lut, fc1b, h);
    fc2_kernel<<<1024, 256, 0, stream>>>(h, fc2w, fc2b, out);
    finalize_kernel<<<1, 256, 0, stream>>>(hpart, lpart, idxp, out);
}